// Round 1
// baseline (4012.544 us; speedup 1.0000x reference)
//
#include <hip/hip_runtime.h>

constexpr float F_Y0     = 0.28209479177387814f;
constexpr float F_CUTOFF = 4.6f;

// ---- order-preserving float<->uint map for atomic max ----
__device__ __forceinline__ unsigned fkey(float f) {
  unsigned u = __float_as_uint(f);
  return (u & 0x80000000u) ? ~u : (u | 0x80000000u);
}
__device__ __forceinline__ float funkey(unsigned k) {
  unsigned u = (k & 0x80000000u) ? (k & 0x7fffffffu) : ~k;
  return __uint_as_float(u);
}
__device__ __forceinline__ float siluf(float v) { return v / (1.0f + expf(-v)); }

__device__ __forceinline__ void load16(const float* p, float* r) {
  const float4* p4 = (const float4*)p;
#pragma unroll
  for (int i = 0; i < 4; i++) {
    float4 t = p4[i];
    r[4*i] = t.x; r[4*i+1] = t.y; r[4*i+2] = t.z; r[4*i+3] = t.w;
  }
}
__device__ __forceinline__ void store16(float* p, const float* r) {
  float4* p4 = (float4*)p;
#pragma unroll
  for (int i = 0; i < 4; i++) p4[i] = make_float4(r[4*i], r[4*i+1], r[4*i+2], r[4*i+3]);
}
__device__ __forceinline__ void load8(const float* p, float* r) {
  const float4* p4 = (const float4*)p;
#pragma unroll
  for (int i = 0; i < 2; i++) {
    float4 t = p4[i];
    r[4*i] = t.x; r[4*i+1] = t.y; r[4*i+2] = t.z; r[4*i+3] = t.w;
  }
}
__device__ __forceinline__ void store8(float* p, const float* r) {
  float4* p4 = (float4*)p;
#pragma unroll
  for (int i = 0; i < 2; i++) p4[i] = make_float4(r[4*i], r[4*i+1], r[4*i+2], r[4*i+3]);
}

// ---------------- per-edge precompute: dist, scale, ef init, Coulomb sum ----------------
__global__ __launch_bounds__(256) void k_pre(
    const int* __restrict__ species, const int* __restrict__ src, const int* __restrict__ dst,
    const float* __restrict__ rel_pos,
    float* __restrict__ dist_, float* __restrict__ scale_, float* __restrict__ ef,
    float* __restrict__ out, int E)
{
  int e = blockIdx.x * 256 + threadIdx.x;
  float ce = 0.0f;
  if (e < E) {
    float px = rel_pos[3*(size_t)e + 0];
    float py = rel_pos[3*(size_t)e + 1];
    float pz = rel_pos[3*(size_t)e + 2];
    float dist = sqrtf(px*px + py*py + pz*pz);
    float xc = dist * (1.0f / F_CUTOFF);
    bool in_cut = dist < F_CUTOFF;
    float x2 = in_cut ? xc * xc : 0.0f;
    x2 = fminf(x2, 1.0f - 1e-6f);
    float sc = in_cut ? expf(3.0f - 3.0f / (1.0f - x2)) : 0.0f;
    dist_[e] = dist;
    scale_[e] = sc;
    float4* efp = (float4*)(ef + (size_t)e * 16);
    float4 z4 = make_float4(0.f, 0.f, 0.f, 0.f);
    efp[0] = z4; efp[1] = z4; efp[2] = z4;
    efp[3] = make_float4(0.f, 0.f, 0.f, dist);
    // Coulomb / ZBL screen (segment_sum then atom-sum == global edge sum)
    float Zu = (float)species[src[e]];
    float Zv = (float)species[dst[e]];
    float raw = 0.529f * Zu * Zv / (2.0f * dist);
    float au = 0.8854f * 0.529f / (powf(Zu, 0.23f) + powf(Zv, 0.23f));
    float xx = dist / au;
    float screen = 0.1818f   * expf(-3.2f    * xx)
                 + 0.5099f   * expf(-0.9423f * xx)
                 + 0.2802f   * expf(-0.4028f * xx)
                 + 0.02817f  * expf(-0.2016f * xx);
    ce = raw * screen * sc;
  }
#pragma unroll
  for (int off = 32; off > 0; off >>= 1) ce += __shfl_down(ce, off, 64);
  if ((threadIdx.x & 63) == 0) atomicAdd(out, ce);
}

// ---------------- node init: x = semb = emb[species-1]; q = x @ Wq0^T ----------------
__global__ __launch_bounds__(256) void k_node_init(
    const int* __restrict__ species, const float* __restrict__ emb,
    const float* __restrict__ Wq0,
    float* __restrict__ x, float* __restrict__ semb, float* __restrict__ q, int N)
{
  int n = blockIdx.x * 256 + threadIdx.x;
  if (n >= N) return;
  int sp = species[n] - 1;
  float xv[16];
  load16(emb + (size_t)sp * 16, xv);
  store16(x + (size_t)n * 16, xv);
  store16(semb + (size_t)n * 16, xv);
  float qv[8];
#pragma unroll
  for (int h = 0; h < 8; h++) {
    float a = 0.f;
#pragma unroll
    for (int i = 0; i < 16; i++) a += Wq0[h * 16 + i] * xv[i];
    qv[h] = a;
  }
  store8(q + (size_t)n * 8, qv);
}

// ---------------- heavy edge conv ----------------
// MODE 0: first layer (ef = [0..0,dist], no ef load/store), writes val/logits/mx
// MODE 1: middle layer (ef += x[src], store ef), writes val/logits/mx
// MODE 2: final conv (ef += x[src], no store), atomicAdd into feats
template <int MODE>
__global__ __launch_bounds__(256) void k_edge_conv(
    const int* __restrict__ src, const int* __restrict__ dst,
    const float* __restrict__ scale_, const float* __restrict__ dist_,
    float* __restrict__ ef, const float* __restrict__ x,
    const float* __restrict__ q,
    const float* __restrict__ W1, const float* __restrict__ B1,
    const float* __restrict__ W2, const float* __restrict__ B2,
    const float* __restrict__ W3, const float* __restrict__ B3,
    float* __restrict__ val, float* __restrict__ logits, unsigned* __restrict__ mx,
    float* __restrict__ feats, int E)
{
  int e = blockIdx.x * 256 + threadIdx.x;
  if (e >= E) return;
  int s = src[e];
  int d = dst[e];
  float xs[16];
  load16(x + (size_t)s * 16, xs);

  float efv[16];
  if (MODE >= 1) {
    float4* efp = (float4*)(ef + (size_t)e * 16);
#pragma unroll
    for (int i = 0; i < 4; i++) {
      float4 t = efp[i];
      efv[4*i]   = t.x + xs[4*i];
      efv[4*i+1] = t.y + xs[4*i+1];
      efv[4*i+2] = t.z + xs[4*i+2];
      efv[4*i+3] = t.w + xs[4*i+3];
    }
    if (MODE == 1) {
#pragma unroll
      for (int i = 0; i < 4; i++)
        efp[i] = make_float4(efv[4*i], efv[4*i+1], efv[4*i+2], efv[4*i+3]);
    }
  }

  // radial MLP: 16 -> 32 -> 32 -> (contracted vs xs)
  float h1[32];
  if (MODE == 0) {
    float dd = dist_[e];
#pragma unroll
    for (int m = 0; m < 32; m++) h1[m] = fmaxf(B1[m] + dd * W1[15 * 32 + m], 0.f);
  } else {
#pragma unroll
    for (int m = 0; m < 32; m++) {
      float a = B1[m];
#pragma unroll
      for (int i = 0; i < 16; i++) a += efv[i] * W1[i * 32 + m];
      h1[m] = fmaxf(a, 0.f);
    }
  }
  float h2[32];
#pragma unroll
  for (int m = 0; m < 32; m++) {
    float a = B2[m];
#pragma unroll
    for (int k = 0; k < 32; k++) a += h1[k] * W2[k * 32 + m];
    h2[m] = fmaxf(a, 0.f);
  }
  // kv[o] = bscale * sum_i (b3[o*16+i] + sum_m h2[m] W3[m,o*16+i]) * xs[i]
  float acc[16];
#pragma unroll
  for (int o = 0; o < 16; o++) {
    float a = 0.f;
#pragma unroll
    for (int i = 0; i < 16; i++) a += B3[o * 16 + i] * xs[i];
    acc[o] = a;
  }
#pragma unroll
  for (int m = 0; m < 32; m++) {
    float hm = h2[m];
#pragma unroll
    for (int o = 0; o < 16; o++) {
      float t = 0.f;
#pragma unroll
      for (int i = 0; i < 16; i++) t += W3[m * 256 + o * 16 + i] * xs[i];
      acc[o] += hm * t;
    }
  }
  float bsc = F_Y0 * scale_[e];

  if (MODE <= 1) {
    float vv[8];
#pragma unroll
    for (int h = 0; h < 8; h++) vv[h] = acc[h] * bsc;
    store8(val + (size_t)e * 8, vv);
    float qd[8];
    load8(q + (size_t)d * 8, qd);
    float lg[8];
#pragma unroll
    for (int h = 0; h < 8; h++) lg[h] = acc[8 + h] * bsc * qd[h];  // dh==1, /sqrt(1)
    store8(logits + (size_t)e * 8, lg);
#pragma unroll
    for (int h = 0; h < 8; h++) atomicMax(&mx[(size_t)d * 8 + h], fkey(lg[h]));
  } else {
#pragma unroll
    for (int o = 0; o < 16; o++) atomicAdd(&feats[(size_t)d * 16 + o], acc[o] * bsc);
  }
}

// ---------------- softmax denom pass: w = scale*exp(lg - mx[dst]); denom += w ----------------
__global__ __launch_bounds__(256) void k_attn_denom(
    const int* __restrict__ dst, const float* __restrict__ scale_,
    float* __restrict__ logits, const unsigned* __restrict__ mx,
    float* __restrict__ denom, int E)
{
  int e = blockIdx.x * 256 + threadIdx.x;
  if (e >= E) return;
  int d = dst[e];
  float sc = scale_[e];
  float lg[8];
  load8(logits + (size_t)e * 8, lg);
  const unsigned* mp = mx + (size_t)d * 8;
  float w[8];
#pragma unroll
  for (int h = 0; h < 8; h++) w[h] = sc * expf(lg[h] - funkey(mp[h]));
  store8(logits + (size_t)e * 8, w);  // overwrite logits with w
#pragma unroll
  for (int h = 0; h < 8; h++) atomicAdd(&denom[(size_t)d * 8 + h], w[h]);
}

// ---------------- aggregation pass: agg[dst] += (w/denom)*val ----------------
__global__ __launch_bounds__(256) void k_attn_agg(
    const int* __restrict__ dst,
    const float* __restrict__ wbuf, const float* __restrict__ denom,
    const float* __restrict__ val, float* __restrict__ agg, int E)
{
  int e = blockIdx.x * 256 + threadIdx.x;
  if (e >= E) return;
  int d = dst[e];
  float w[8], vv[8], dn[8];
  load8(wbuf + (size_t)e * 8, w);
  load8(val + (size_t)e * 8, vv);
  load8(denom + (size_t)d * 8, dn);
#pragma unroll
  for (int h = 0; h < 8; h++) {
    float attn = w[h] / fmaxf(dn[h], 1e-20f);
    atomicAdd(&agg[(size_t)d * 8 + h], attn * vv[h]);
  }
}

// ---------------- node update: x_out = [agg, x_in] @ Wproj^T ; q = x_out @ Wq_next^T ----------------
__global__ __launch_bounds__(256) void k_node_update(
    const float* __restrict__ agg, const float* __restrict__ xin,
    const float* __restrict__ Wproj, const float* __restrict__ Wq_next,
    float* __restrict__ xout, float* __restrict__ q, int N)
{
  int n = blockIdx.x * 256 + threadIdx.x;
  if (n >= N) return;
  float cat[24];
  load8(agg + (size_t)n * 8, cat);
  load16(xin + (size_t)n * 16, cat + 8);
  float xn[16];
#pragma unroll
  for (int o = 0; o < 16; o++) {
    float a = 0.f;
#pragma unroll
    for (int j = 0; j < 24; j++) a += Wproj[o * 24 + j] * cat[j];
    xn[o] = a;
  }
  store16(xout + (size_t)n * 16, xn);
  float qv[8];
#pragma unroll
  for (int h = 0; h < 8; h++) {
    float a = 0.f;
#pragma unroll
    for (int i = 0; i < 16; i++) a += Wq_next[h * 16 + i] * xn[i];
    qv[h] = a;
  }
  store8(q + (size_t)n * 8, qv);
}

// ---------------- final node MLP + energy reduction ----------------
__global__ __launch_bounds__(256) void k_node_final(
    const float* __restrict__ x, const float* __restrict__ semb,
    const float* __restrict__ feats, const float* __restrict__ Wself,
    const float* __restrict__ mW1, const float* __restrict__ mb1,
    const float* __restrict__ mW2, const float* __restrict__ mb2,
    const float* __restrict__ mW3, const float* __restrict__ mb3,
    float* __restrict__ out, int N)
{
  int n = blockIdx.x * 256 + threadIdx.x;
  float learned = 0.f;
  if (n < N) {
    float xv[16], ft[16], sb[16];
    load16(x + (size_t)n * 16, xv);
    load16(feats + (size_t)n * 16, ft);
    load16(semb + (size_t)n * 16, sb);
    float cat[32];
#pragma unroll
    for (int i = 0; i < 16; i++) cat[i] = sb[i];
#pragma unroll
    for (int o = 0; o < 16; o++) {
      float a = ft[o];
#pragma unroll
      for (int i = 0; i < 16; i++) a += Wself[o * 16 + i] * xv[i];
      cat[16 + o] = a;
    }
    float hh[16];
#pragma unroll
    for (int j = 0; j < 16; j++) {
      float a = mb1[j];
#pragma unroll
      for (int k = 0; k < 32; k++) a += cat[k] * mW1[k * 16 + j];
      hh[j] = siluf(a);
    }
    float h2[16];
#pragma unroll
    for (int j = 0; j < 16; j++) {
      float a = mb2[j];
#pragma unroll
      for (int k = 0; k < 16; k++) a += hh[k] * mW2[k * 16 + j];
      h2[j] = siluf(a);
    }
    float a = mb3[0];
#pragma unroll
    for (int k = 0; k < 16; k++) a += h2[k] * mW3[k];
    learned = a;
  }
#pragma unroll
  for (int off = 32; off > 0; off >>= 1) learned += __shfl_down(learned, off, 64);
  if ((threadIdx.x & 63) == 0) atomicAdd(out, learned);
}

extern "C" void kernel_launch(void* const* d_in, const int* in_sizes, int n_in,
                              void* d_out, int out_size, void* d_ws, size_t ws_size,
                              hipStream_t stream)
{
  const int*   species = (const int*)d_in[0];
  const int*   src     = (const int*)d_in[1];
  const int*   dst     = (const int*)d_in[2];
  const float* rel_pos = (const float*)d_in[3];
  const float* emb     = (const float*)d_in[4];
  const float* kv_W1   = (const float*)d_in[5];
  const float* kv_b1   = (const float*)d_in[6];
  const float* kv_W2   = (const float*)d_in[7];
  const float* kv_b2   = (const float*)d_in[8];
  const float* kv_W3   = (const float*)d_in[9];
  const float* kv_b3   = (const float*)d_in[10];
  const float* Wq      = (const float*)d_in[11];
  const float* Wproj   = (const float*)d_in[12];
  const float* fin_W1  = (const float*)d_in[13];
  const float* fin_b1  = (const float*)d_in[14];
  const float* fin_W2  = (const float*)d_in[15];
  const float* fin_b2  = (const float*)d_in[16];
  const float* fin_W3  = (const float*)d_in[17];
  const float* fin_b3  = (const float*)d_in[18];
  const float* Wself   = (const float*)d_in[19];
  const float* mlp_W1  = (const float*)d_in[20];
  const float* mlp_b1  = (const float*)d_in[21];
  const float* mlp_W2  = (const float*)d_in[22];
  const float* mlp_b2  = (const float*)d_in[23];
  const float* mlp_W3  = (const float*)d_in[24];
  const float* mlp_b3  = (const float*)d_in[25];

  const int N = in_sizes[0];
  const int E = in_sizes[1];

  char* p = (char*)d_ws;
  auto alloc = [&](size_t bytes) -> void* {
    void* r = (void*)p;
    p += (bytes + 255) & ~(size_t)255;
    return r;
  };
  float*    dist_  = (float*)alloc((size_t)E * 4);
  float*    scale_ = (float*)alloc((size_t)E * 4);
  float*    ef     = (float*)alloc((size_t)E * 16 * 4);
  float*    xA     = (float*)alloc((size_t)N * 16 * 4);
  float*    xB     = (float*)alloc((size_t)N * 16 * 4);
  float*    q      = (float*)alloc((size_t)N * 8 * 4);
  float*    semb   = (float*)alloc((size_t)N * 16 * 4);
  float*    val    = (float*)alloc((size_t)E * 8 * 4);
  float*    logits = (float*)alloc((size_t)E * 8 * 4);
  // mx, denom, agg are contiguous (each N*8*4 bytes, 256-aligned) -> single memset
  unsigned* mx     = (unsigned*)alloc((size_t)N * 8 * 4);
  float*    denom  = (float*)alloc((size_t)N * 8 * 4);
  float*    agg    = (float*)alloc((size_t)N * 8 * 4);
  float*    feats  = (float*)alloc((size_t)N * 16 * 4);

  dim3 blk(256);
  dim3 egrid((E + 255) / 256);
  dim3 ngrid((N + 255) / 256);

  hipMemsetAsync(d_out, 0, sizeof(float), stream);

  k_pre<<<egrid, blk, 0, stream>>>(species, src, dst, rel_pos, dist_, scale_, ef,
                                   (float*)d_out, E);
  k_node_init<<<ngrid, blk, 0, stream>>>(species, emb, Wq, xA, semb, q, N);

  float* xin = xA;
  float* xout = xB;
  for (int l = 0; l < 4; l++) {
    hipMemsetAsync(mx, 0, (size_t)N * 8 * 4 * 3, stream);  // mx + denom + agg
    const float* W1 = kv_W1 + (size_t)l * 16 * 32;
    const float* B1 = kv_b1 + (size_t)l * 32;
    const float* W2 = kv_W2 + (size_t)l * 32 * 32;
    const float* B2 = kv_b2 + (size_t)l * 32;
    const float* W3 = kv_W3 + (size_t)l * 32 * 256;
    const float* B3 = kv_b3 + (size_t)l * 256;
    const float* Wqn = Wq + (size_t)((l < 3) ? (l + 1) : 0) * 8 * 16;
    if (l == 0) {
      k_edge_conv<0><<<egrid, blk, 0, stream>>>(src, dst, scale_, dist_, ef, xin, q,
                                                W1, B1, W2, B2, W3, B3,
                                                val, logits, mx, nullptr, E);
    } else {
      k_edge_conv<1><<<egrid, blk, 0, stream>>>(src, dst, scale_, dist_, ef, xin, q,
                                                W1, B1, W2, B2, W3, B3,
                                                val, logits, mx, nullptr, E);
    }
    k_attn_denom<<<egrid, blk, 0, stream>>>(dst, scale_, logits, mx, denom, E);
    k_attn_agg<<<egrid, blk, 0, stream>>>(dst, logits, denom, val, agg, E);
    k_node_update<<<ngrid, blk, 0, stream>>>(agg, xin, Wproj + (size_t)l * 16 * 24, Wqn,
                                             xout, q, N);
    float* tmp = xin; xin = xout; xout = tmp;
  }

  hipMemsetAsync(feats, 0, (size_t)N * 16 * 4, stream);
  k_edge_conv<2><<<egrid, blk, 0, stream>>>(src, dst, scale_, dist_, ef, xin, q,
                                            fin_W1, fin_b1, fin_W2, fin_b2, fin_W3, fin_b3,
                                            nullptr, nullptr, nullptr, feats, E);
  k_node_final<<<ngrid, blk, 0, stream>>>(xin, semb, feats, Wself,
                                          mlp_W1, mlp_b1, mlp_W2, mlp_b2, mlp_W3, mlp_b3,
                                          (float*)d_out, N);
}

// Round 2
// 3638.963 us; speedup vs baseline: 1.1027x; 1.1027x over previous
//
#include <hip/hip_runtime.h>

constexpr float F_Y0     = 0.28209479177387814f;
constexpr float F_CUTOFF = 4.6f;

// ---- order-preserving float<->uint map for atomic max ----
__device__ __forceinline__ unsigned fkey(float f) {
  unsigned u = __float_as_uint(f);
  return (u & 0x80000000u) ? ~u : (u | 0x80000000u);
}
__device__ __forceinline__ float funkey(unsigned k) {
  unsigned u = (k & 0x80000000u) ? (k & 0x7fffffffu) : ~k;
  return __uint_as_float(u);
}
__device__ __forceinline__ float siluf(float v) { return v / (1.0f + expf(-v)); }

__device__ __forceinline__ void load16(const float* p, float* r) {
  const float4* p4 = (const float4*)p;
#pragma unroll
  for (int i = 0; i < 4; i++) {
    float4 t = p4[i];
    r[4*i] = t.x; r[4*i+1] = t.y; r[4*i+2] = t.z; r[4*i+3] = t.w;
  }
}
__device__ __forceinline__ void store16(float* p, const float* r) {
  float4* p4 = (float4*)p;
#pragma unroll
  for (int i = 0; i < 4; i++) p4[i] = make_float4(r[4*i], r[4*i+1], r[4*i+2], r[4*i+3]);
}
__device__ __forceinline__ void load8(const float* p, float* r) {
  const float4* p4 = (const float4*)p;
#pragma unroll
  for (int i = 0; i < 2; i++) {
    float4 t = p4[i];
    r[4*i] = t.x; r[4*i+1] = t.y; r[4*i+2] = t.z; r[4*i+3] = t.w;
  }
}
__device__ __forceinline__ void store8(float* p, const float* r) {
  float4* p4 = (float4*)p;
#pragma unroll
  for (int i = 0; i < 2; i++) p4[i] = make_float4(r[4*i], r[4*i+1], r[4*i+2], r[4*i+3]);
}

// ---------------- per-edge precompute: dist, scale, Coulomb sum ----------------
__global__ __launch_bounds__(256) void k_pre(
    const int* __restrict__ species, const int* __restrict__ src, const int* __restrict__ dst,
    const float* __restrict__ rel_pos,
    float* __restrict__ dist_, float* __restrict__ scale_,
    float* __restrict__ out, int E)
{
  int e = blockIdx.x * 256 + threadIdx.x;
  float ce = 0.0f;
  if (e < E) {
    float px = rel_pos[3*(size_t)e + 0];
    float py = rel_pos[3*(size_t)e + 1];
    float pz = rel_pos[3*(size_t)e + 2];
    float dist = sqrtf(px*px + py*py + pz*pz);
    float xc = dist * (1.0f / F_CUTOFF);
    bool in_cut = dist < F_CUTOFF;
    float x2 = in_cut ? xc * xc : 0.0f;
    x2 = fminf(x2, 1.0f - 1e-6f);
    float sc = in_cut ? expf(3.0f - 3.0f / (1.0f - x2)) : 0.0f;
    dist_[e] = dist;
    scale_[e] = sc;
    // Coulomb / ZBL screen (segment_sum then atom-sum == global edge sum)
    float Zu = (float)species[src[e]];
    float Zv = (float)species[dst[e]];
    float raw = 0.529f * Zu * Zv / (2.0f * dist);
    float au = 0.8854f * 0.529f / (powf(Zu, 0.23f) + powf(Zv, 0.23f));
    float xx = dist / au;
    float screen = 0.1818f   * expf(-3.2f    * xx)
                 + 0.5099f   * expf(-0.9423f * xx)
                 + 0.2802f   * expf(-0.4028f * xx)
                 + 0.02817f  * expf(-0.2016f * xx);
    ce = raw * screen * sc;
  }
#pragma unroll
  for (int off = 32; off > 0; off >>= 1) ce += __shfl_down(ce, off, 64);
  if ((threadIdx.x & 63) == 0) atomicAdd(out, ce);
}

// ---------------- node init: x = semb = emb[species-1]; q = x @ Wq0^T ----------------
__global__ __launch_bounds__(256) void k_node_init(
    const int* __restrict__ species, const float* __restrict__ emb,
    const float* __restrict__ Wq0,
    float* __restrict__ x, float* __restrict__ semb, float* __restrict__ q, int N)
{
  int n = blockIdx.x * 256 + threadIdx.x;
  if (n >= N) return;
  int sp = species[n] - 1;
  float xv[16];
  load16(emb + (size_t)sp * 16, xv);
  store16(x + (size_t)n * 16, xv);
  store16(semb + (size_t)n * 16, xv);
  float qv[8];
#pragma unroll
  for (int h = 0; h < 8; h++) {
    float a = 0.f;
#pragma unroll
    for (int i = 0; i < 16; i++) a += Wq0[h * 16 + i] * xv[i];
    qv[h] = a;
  }
  store8(q + (size_t)n * 8, qv);
}

// ---------------- heavy edge conv ----------------
// MODE 0: layer 0  (ef = [0..0,dist] -> h1 from dist only), writes valT/lgT/mx
// MODE 1: layer 1  (ef = dist-init + x[src], reconstructed from dist_, store ef)
// MODE 2: layer 2,3 (ef load + x[src], store ef)
// MODE 3: final conv (ef load + x[src], no store), atomicAdd into feats
template <int MODE>
__global__ __launch_bounds__(256, 4) void k_edge_conv(
    const int* __restrict__ src, const int* __restrict__ dst,
    const float* __restrict__ scale_, const float* __restrict__ dist_,
    float* __restrict__ ef, const float* __restrict__ x,
    const float* __restrict__ q,
    const float* __restrict__ W1, const float* __restrict__ B1,
    const float* __restrict__ W2, const float* __restrict__ B2,
    const float* __restrict__ W3, const float* __restrict__ B3,
    float* __restrict__ valT, float* __restrict__ lgT, unsigned* __restrict__ mx,
    float* __restrict__ feats, int E)
{
  int e = blockIdx.x * 256 + threadIdx.x;
  if (e >= E) return;
  int s = src[e];
  int d = dst[e];
  float xs[16];
  load16(x + (size_t)s * 16, xs);

  float h2[32];
  {
    float h1[32];
    if (MODE == 0) {
      float dd = dist_[e];
#pragma unroll
      for (int m = 0; m < 32; m++) h1[m] = fmaxf(B1[m] + dd * W1[15 * 32 + m], 0.f);
    } else {
      float efv[16];
      if (MODE == 1) {
#pragma unroll
        for (int i = 0; i < 16; i++) efv[i] = xs[i];
        efv[15] += dist_[e];
      } else {
        float4* efp = (float4*)(ef + (size_t)e * 16);
#pragma unroll
        for (int i = 0; i < 4; i++) {
          float4 t = efp[i];
          efv[4*i]   = t.x + xs[4*i];
          efv[4*i+1] = t.y + xs[4*i+1];
          efv[4*i+2] = t.z + xs[4*i+2];
          efv[4*i+3] = t.w + xs[4*i+3];
        }
      }
      if (MODE == 1 || MODE == 2) {
        float4* efp = (float4*)(ef + (size_t)e * 16);
#pragma unroll
        for (int i = 0; i < 4; i++)
          efp[i] = make_float4(efv[4*i], efv[4*i+1], efv[4*i+2], efv[4*i+3]);
      }
#pragma unroll
      for (int m = 0; m < 32; m++) {
        float a = B1[m];
#pragma unroll
        for (int i = 0; i < 16; i++) a += efv[i] * W1[i * 32 + m];
        h1[m] = fmaxf(a, 0.f);
      }
    }
#pragma unroll
    for (int m = 0; m < 32; m++) {
      float a = B2[m];
#pragma unroll
      for (int k = 0; k < 32; k++) a += h1[k] * W2[k * 32 + m];
      h2[m] = fmaxf(a, 0.f);
    }
  }

  float bsc = F_Y0 * scale_[e];

  // kv[o] = bscale * (B3[o,:] + sum_m h2[m] W3[m,o,:]) . xs
  // runtime o-loop: small code footprint, ~50 live VGPRs, W3/B3 via SGPR s_loads
#pragma unroll 1
  for (int o = 0; o < 16; ++o) {
    float a = 0.f;
#pragma unroll
    for (int i = 0; i < 16; i++) a += B3[o * 16 + i] * xs[i];
#pragma unroll
    for (int m = 0; m < 32; m++) {
      float t = 0.f;
#pragma unroll
      for (int i = 0; i < 16; i++) t += W3[m * 256 + o * 16 + i] * xs[i];
      a += h2[m] * t;
    }
    a *= bsc;
    if (MODE <= 2) {
      if (o < 8) {
        valT[(size_t)o * E + e] = a;
      } else {
        int h = o - 8;
        float lg = a * q[(size_t)d * 8 + h];   // dh==1, /sqrt(1)
        lgT[(size_t)h * E + e] = lg;
        atomicMax(&mx[(size_t)d * 8 + h], fkey(lg));
      }
    } else {
      atomicAdd(&feats[(size_t)d * 16 + o], a);
    }
  }
}

// ---------------- softmax denom pass (2D grid: x=edges, y=head) ----------------
__global__ __launch_bounds__(256) void k_attn_denom(
    const int* __restrict__ dst, const float* __restrict__ scale_,
    float* __restrict__ lgT, const unsigned* __restrict__ mx,
    float* __restrict__ denom, int E)
{
  int e = blockIdx.x * 256 + threadIdx.x;
  if (e >= E) return;
  int h = blockIdx.y;
  int d = dst[e];
  float w = scale_[e] * expf(lgT[(size_t)h * E + e] - funkey(mx[(size_t)d * 8 + h]));
  lgT[(size_t)h * E + e] = w;  // overwrite logits with w
  atomicAdd(&denom[(size_t)d * 8 + h], w);
}

// ---------------- aggregation pass: agg[dst] += (w/denom)*val ----------------
__global__ __launch_bounds__(256) void k_attn_agg(
    const int* __restrict__ dst,
    const float* __restrict__ wT, const float* __restrict__ denom,
    const float* __restrict__ valT, float* __restrict__ agg, int E)
{
  int e = blockIdx.x * 256 + threadIdx.x;
  if (e >= E) return;
  int h = blockIdx.y;
  int d = dst[e];
  float w = wT[(size_t)h * E + e];
  float dn = denom[(size_t)d * 8 + h];
  float attn = w / fmaxf(dn, 1e-20f);
  atomicAdd(&agg[(size_t)d * 8 + h], attn * valT[(size_t)h * E + e]);
}

// ---------------- node update: x_out = [agg, x_in] @ Wproj^T ; q = x_out @ Wq_next^T ----------------
__global__ __launch_bounds__(256) void k_node_update(
    const float* __restrict__ agg, const float* __restrict__ xin,
    const float* __restrict__ Wproj, const float* __restrict__ Wq_next,
    float* __restrict__ xout, float* __restrict__ q, int N)
{
  int n = blockIdx.x * 256 + threadIdx.x;
  if (n >= N) return;
  float cat[24];
  load8(agg + (size_t)n * 8, cat);
  load16(xin + (size_t)n * 16, cat + 8);
  float xn[16];
#pragma unroll
  for (int o = 0; o < 16; o++) {
    float a = 0.f;
#pragma unroll
    for (int j = 0; j < 24; j++) a += Wproj[o * 24 + j] * cat[j];
    xn[o] = a;
  }
  store16(xout + (size_t)n * 16, xn);
  float qv[8];
#pragma unroll
  for (int h = 0; h < 8; h++) {
    float a = 0.f;
#pragma unroll
    for (int i = 0; i < 16; i++) a += Wq_next[h * 16 + i] * xn[i];
    qv[h] = a;
  }
  store8(q + (size_t)n * 8, qv);
}

// ---------------- final node MLP + energy reduction ----------------
__global__ __launch_bounds__(256) void k_node_final(
    const float* __restrict__ x, const float* __restrict__ semb,
    const float* __restrict__ feats, const float* __restrict__ Wself,
    const float* __restrict__ mW1, const float* __restrict__ mb1,
    const float* __restrict__ mW2, const float* __restrict__ mb2,
    const float* __restrict__ mW3, const float* __restrict__ mb3,
    float* __restrict__ out, int N)
{
  int n = blockIdx.x * 256 + threadIdx.x;
  float learned = 0.f;
  if (n < N) {
    float xv[16], ft[16], sb[16];
    load16(x + (size_t)n * 16, xv);
    load16(feats + (size_t)n * 16, ft);
    load16(semb + (size_t)n * 16, sb);
    float cat[32];
#pragma unroll
    for (int i = 0; i < 16; i++) cat[i] = sb[i];
#pragma unroll
    for (int o = 0; o < 16; o++) {
      float a = ft[o];
#pragma unroll
      for (int i = 0; i < 16; i++) a += Wself[o * 16 + i] * xv[i];
      cat[16 + o] = a;
    }
    float hh[16];
#pragma unroll
    for (int j = 0; j < 16; j++) {
      float a = mb1[j];
#pragma unroll
      for (int k = 0; k < 32; k++) a += cat[k] * mW1[k * 16 + j];
      hh[j] = siluf(a);
    }
    float h2[16];
#pragma unroll
    for (int j = 0; j < 16; j++) {
      float a = mb2[j];
#pragma unroll
      for (int k = 0; k < 16; k++) a += hh[k] * mW2[k * 16 + j];
      h2[j] = siluf(a);
    }
    float a = mb3[0];
#pragma unroll
    for (int k = 0; k < 16; k++) a += h2[k] * mW3[k];
    learned = a;
  }
#pragma unroll
  for (int off = 32; off > 0; off >>= 1) learned += __shfl_down(learned, off, 64);
  if ((threadIdx.x & 63) == 0) atomicAdd(out, learned);
}

extern "C" void kernel_launch(void* const* d_in, const int* in_sizes, int n_in,
                              void* d_out, int out_size, void* d_ws, size_t ws_size,
                              hipStream_t stream)
{
  const int*   species = (const int*)d_in[0];
  const int*   src     = (const int*)d_in[1];
  const int*   dst     = (const int*)d_in[2];
  const float* rel_pos = (const float*)d_in[3];
  const float* emb     = (const float*)d_in[4];
  const float* kv_W1   = (const float*)d_in[5];
  const float* kv_b1   = (const float*)d_in[6];
  const float* kv_W2   = (const float*)d_in[7];
  const float* kv_b2   = (const float*)d_in[8];
  const float* kv_W3   = (const float*)d_in[9];
  const float* kv_b3   = (const float*)d_in[10];
  const float* Wq      = (const float*)d_in[11];
  const float* Wproj   = (const float*)d_in[12];
  const float* fin_W1  = (const float*)d_in[13];
  const float* fin_b1  = (const float*)d_in[14];
  const float* fin_W2  = (const float*)d_in[15];
  const float* fin_b2  = (const float*)d_in[16];
  const float* fin_W3  = (const float*)d_in[17];
  const float* fin_b3  = (const float*)d_in[18];
  const float* Wself   = (const float*)d_in[19];
  const float* mlp_W1  = (const float*)d_in[20];
  const float* mlp_b1  = (const float*)d_in[21];
  const float* mlp_W2  = (const float*)d_in[22];
  const float* mlp_b2  = (const float*)d_in[23];
  const float* mlp_W3  = (const float*)d_in[24];
  const float* mlp_b3  = (const float*)d_in[25];

  const int N = in_sizes[0];
  const int E = in_sizes[1];

  char* p = (char*)d_ws;
  auto alloc = [&](size_t bytes) -> void* {
    void* r = (void*)p;
    p += (bytes + 255) & ~(size_t)255;
    return r;
  };
  float*    dist_  = (float*)alloc((size_t)E * 4);
  float*    scale_ = (float*)alloc((size_t)E * 4);
  float*    ef     = (float*)alloc((size_t)E * 16 * 4);
  float*    xA     = (float*)alloc((size_t)N * 16 * 4);
  float*    xB     = (float*)alloc((size_t)N * 16 * 4);
  float*    q      = (float*)alloc((size_t)N * 8 * 4);
  float*    semb   = (float*)alloc((size_t)N * 16 * 4);
  float*    valT   = (float*)alloc((size_t)E * 8 * 4);   // [h][e]
  float*    lgT    = (float*)alloc((size_t)E * 8 * 4);   // [h][e]
  // mx, denom, agg are contiguous (each N*8*4 bytes, 256-aligned) -> single memset
  unsigned* mx     = (unsigned*)alloc((size_t)N * 8 * 4);
  float*    denom  = (float*)alloc((size_t)N * 8 * 4);
  float*    agg    = (float*)alloc((size_t)N * 8 * 4);
  float*    feats  = (float*)alloc((size_t)N * 16 * 4);

  dim3 blk(256);
  dim3 egrid((E + 255) / 256);
  dim3 egrid8((E + 255) / 256, 8);
  dim3 ngrid((N + 255) / 256);

  hipMemsetAsync(d_out, 0, sizeof(float), stream);

  k_pre<<<egrid, blk, 0, stream>>>(species, src, dst, rel_pos, dist_, scale_,
                                   (float*)d_out, E);
  k_node_init<<<ngrid, blk, 0, stream>>>(species, emb, Wq, xA, semb, q, N);

  float* xin = xA;
  float* xout = xB;
  for (int l = 0; l < 4; l++) {
    hipMemsetAsync(mx, 0, (size_t)N * 8 * 4 * 3, stream);  // mx + denom + agg
    const float* W1 = kv_W1 + (size_t)l * 16 * 32;
    const float* B1 = kv_b1 + (size_t)l * 32;
    const float* W2 = kv_W2 + (size_t)l * 32 * 32;
    const float* B2 = kv_b2 + (size_t)l * 32;
    const float* W3 = kv_W3 + (size_t)l * 32 * 256;
    const float* B3 = kv_b3 + (size_t)l * 256;
    const float* Wqn = Wq + (size_t)((l < 3) ? (l + 1) : 0) * 8 * 16;
    if (l == 0) {
      k_edge_conv<0><<<egrid, blk, 0, stream>>>(src, dst, scale_, dist_, ef, xin, q,
                                                W1, B1, W2, B2, W3, B3,
                                                valT, lgT, mx, nullptr, E);
    } else if (l == 1) {
      k_edge_conv<1><<<egrid, blk, 0, stream>>>(src, dst, scale_, dist_, ef, xin, q,
                                                W1, B1, W2, B2, W3, B3,
                                                valT, lgT, mx, nullptr, E);
    } else {
      k_edge_conv<2><<<egrid, blk, 0, stream>>>(src, dst, scale_, dist_, ef, xin, q,
                                                W1, B1, W2, B2, W3, B3,
                                                valT, lgT, mx, nullptr, E);
    }
    k_attn_denom<<<egrid8, blk, 0, stream>>>(dst, scale_, lgT, mx, denom, E);
    k_attn_agg<<<egrid8, blk, 0, stream>>>(dst, lgT, denom, valT, agg, E);
    k_node_update<<<ngrid, blk, 0, stream>>>(agg, xin, Wproj + (size_t)l * 16 * 24, Wqn,
                                             xout, q, N);
    float* tmp = xin; xin = xout; xout = tmp;
  }

  hipMemsetAsync(feats, 0, (size_t)N * 16 * 4, stream);
  k_edge_conv<3><<<egrid, blk, 0, stream>>>(src, dst, scale_, dist_, ef, xin, q,
                                            fin_W1, fin_b1, fin_W2, fin_b2, fin_W3, fin_b3,
                                            nullptr, nullptr, nullptr, feats, E);
  k_node_final<<<ngrid, blk, 0, stream>>>(xin, semb, feats, Wself,
                                          mlp_W1, mlp_b1, mlp_W2, mlp_b2, mlp_W3, mlp_b3,
                                          (float*)d_out, N);
}

// Round 3
// 1917.910 us; speedup vs baseline: 2.0921x; 1.8974x over previous
//
#include <hip/hip_runtime.h>

constexpr float F_Y0     = 0.28209479177387814f;
constexpr float F_CUTOFF = 4.6f;

__device__ __forceinline__ float siluf(float v) { return v / (1.0f + expf(-v)); }

__device__ __forceinline__ void load16(const float* p, float* r) {
  const float4* p4 = (const float4*)p;
#pragma unroll
  for (int i = 0; i < 4; i++) {
    float4 t = p4[i];
    r[4*i] = t.x; r[4*i+1] = t.y; r[4*i+2] = t.z; r[4*i+3] = t.w;
  }
}
__device__ __forceinline__ void store16(float* p, const float* r) {
  float4* p4 = (float4*)p;
#pragma unroll
  for (int i = 0; i < 4; i++) p4[i] = make_float4(r[4*i], r[4*i+1], r[4*i+2], r[4*i+3]);
}
__device__ __forceinline__ void load8(const float* p, float* r) {
  const float4* p4 = (const float4*)p;
#pragma unroll
  for (int i = 0; i < 2; i++) {
    float4 t = p4[i];
    r[4*i] = t.x; r[4*i+1] = t.y; r[4*i+2] = t.z; r[4*i+3] = t.w;
  }
}
__device__ __forceinline__ void store8(float* p, const float* r) {
  float4* p4 = (float4*)p;
#pragma unroll
  for (int i = 0; i < 2; i++) p4[i] = make_float4(r[4*i], r[4*i+1], r[4*i+2], r[4*i+3]);
}

// ---------------- per-edge precompute: dist, scale, Coulomb sum ----------------
__global__ __launch_bounds__(256) void k_pre(
    const int* __restrict__ species, const int* __restrict__ src, const int* __restrict__ dst,
    const float* __restrict__ rel_pos,
    float* __restrict__ dist_, float* __restrict__ scale_,
    float* __restrict__ out, int E)
{
  int e = blockIdx.x * 256 + threadIdx.x;
  float ce = 0.0f;
  if (e < E) {
    float px = rel_pos[3*(size_t)e + 0];
    float py = rel_pos[3*(size_t)e + 1];
    float pz = rel_pos[3*(size_t)e + 2];
    float dist = sqrtf(px*px + py*py + pz*pz);
    float xc = dist * (1.0f / F_CUTOFF);
    bool in_cut = dist < F_CUTOFF;
    float x2 = in_cut ? xc * xc : 0.0f;
    x2 = fminf(x2, 1.0f - 1e-6f);
    float sc = in_cut ? expf(3.0f - 3.0f / (1.0f - x2)) : 0.0f;
    dist_[e] = dist;
    scale_[e] = sc;
    float Zu = (float)species[src[e]];
    float Zv = (float)species[dst[e]];
    float raw = 0.529f * Zu * Zv / (2.0f * dist);
    float au = 0.8854f * 0.529f / (powf(Zu, 0.23f) + powf(Zv, 0.23f));
    float xx = dist / au;
    float screen = 0.1818f   * expf(-3.2f    * xx)
                 + 0.5099f   * expf(-0.9423f * xx)
                 + 0.2802f   * expf(-0.4028f * xx)
                 + 0.02817f  * expf(-0.2016f * xx);
    ce = raw * screen * sc;
  }
#pragma unroll
  for (int off = 32; off > 0; off >>= 1) ce += __shfl_down(ce, off, 64);
  if ((threadIdx.x & 63) == 0) atomicAdd(out, ce);
}

// ---------------- CSR build ----------------
__global__ __launch_bounds__(256) void k_hist(
    const int* __restrict__ dst, int* __restrict__ cnt, int E)
{
  int e = blockIdx.x * 256 + threadIdx.x;
  if (e < E) atomicAdd(&cnt[dst[e]], 1);
}

// per-block exclusive scan of cnt (256/node block); bsum[b] = block total
__global__ __launch_bounds__(256) void k_scan1(
    const int* __restrict__ cnt, int* __restrict__ row_ptr, int* __restrict__ bsum)
{
  __shared__ int s[256];
  int tid = threadIdx.x;
  int n = blockIdx.x * 256 + tid;
  int v = cnt[n];
  s[tid] = v;
  __syncthreads();
#pragma unroll
  for (int off = 1; off < 256; off <<= 1) {
    int t = (tid >= off) ? s[tid - off] : 0;
    __syncthreads();
    s[tid] += t;
    __syncthreads();
  }
  row_ptr[n] = s[tid] - v;          // exclusive within block
  if (tid == 255) bsum[blockIdx.x] = s[255];
}

// single-block exclusive scan of 128 block sums
__global__ __launch_bounds__(128) void k_scan2(int* __restrict__ bsum, int* __restrict__ boff)
{
  __shared__ int s[128];
  int tid = threadIdx.x;
  int v = bsum[tid];
  s[tid] = v;
  __syncthreads();
#pragma unroll
  for (int off = 1; off < 128; off <<= 1) {
    int t = (tid >= off) ? s[tid - off] : 0;
    __syncthreads();
    s[tid] += t;
    __syncthreads();
  }
  boff[tid] = s[tid] - v;           // exclusive
}

__global__ __launch_bounds__(256) void k_scan3(
    int* __restrict__ row_ptr, int* __restrict__ row_cur,
    const int* __restrict__ boff, int N, int E)
{
  int n = blockIdx.x * 256 + threadIdx.x;
  int rp = row_ptr[n] + boff[blockIdx.x];
  row_ptr[n] = rp;
  row_cur[n] = rp;
  if (n == 0) row_ptr[N] = E;
}

// scatter edge payloads into dst-sorted order
__global__ __launch_bounds__(256) void k_scatter(
    const int* __restrict__ src, const int* __restrict__ dst,
    const float* __restrict__ dist_, const float* __restrict__ scale_,
    int* __restrict__ row_cur,
    int* __restrict__ srcP, float* __restrict__ distP, float* __restrict__ scaleP, int E)
{
  int e = blockIdx.x * 256 + threadIdx.x;
  if (e >= E) return;
  int d = dst[e];
  int pos = atomicAdd(&row_cur[d], 1);
  srcP[pos] = src[e];
  distP[pos] = dist_[e];
  scaleP[pos] = scale_[e];
}

// ---------------- node init: x = semb = emb[species-1]; q = x @ Wq0^T ----------------
__global__ __launch_bounds__(256) void k_node_init(
    const int* __restrict__ species, const float* __restrict__ emb,
    const float* __restrict__ Wq0,
    float* __restrict__ x, float* __restrict__ semb, float* __restrict__ q, int N)
{
  int n = blockIdx.x * 256 + threadIdx.x;
  if (n >= N) return;
  int sp = species[n] - 1;
  float xv[16];
  load16(emb + (size_t)sp * 16, xv);
  store16(x + (size_t)n * 16, xv);
  store16(semb + (size_t)n * 16, xv);
  float qv[8];
#pragma unroll
  for (int h = 0; h < 8; h++) {
    float a = 0.f;
#pragma unroll
    for (int i = 0; i < 16; i++) a += Wq0[h * 16 + i] * xv[i];
    qv[h] = a;
  }
  store8(q + (size_t)n * 8, qv);
}

// ---------------- heavy edge conv (permuted edge space, atomic-free) ----------------
// MODE 0: layer 0  (h1 from dist only)
// MODE 1: layer 1  (ef = x[src] + dist-init, store ef)
// MODE 2: layer 2,3 (ef load + x[src], store ef)
// MODE 3: final conv (ef load + x[src], no store)
// Writes kvT[o][i] for all 16 o (val rows 0..7, key rows 8..15; MODE3: all conv out)
template <int MODE>
__global__ __launch_bounds__(256) void k_edge_conv(
    const int* __restrict__ srcP,
    const float* __restrict__ scaleP, const float* __restrict__ distP,
    float* __restrict__ ef, const float* __restrict__ x,
    const float* __restrict__ W1, const float* __restrict__ B1,
    const float* __restrict__ W2, const float* __restrict__ B2,
    const float* __restrict__ W3, const float* __restrict__ B3,
    float* __restrict__ kvT, int E)
{
  int i = blockIdx.x * 256 + threadIdx.x;
  if (i >= E) return;
  int s = srcP[i];
  float xs[16];
  load16(x + (size_t)s * 16, xs);

  float h2[32];
  {
    float h1[32];
    if (MODE == 0) {
      float dd = distP[i];
#pragma unroll
      for (int m = 0; m < 32; m++) h1[m] = fmaxf(B1[m] + dd * W1[15 * 32 + m], 0.f);
    } else {
      float efv[16];
      if (MODE == 1) {
#pragma unroll
        for (int ii = 0; ii < 16; ii++) efv[ii] = xs[ii];
        efv[15] += distP[i];
      } else {
        float4* efp = (float4*)(ef + (size_t)i * 16);
#pragma unroll
        for (int ii = 0; ii < 4; ii++) {
          float4 t = efp[ii];
          efv[4*ii]   = t.x + xs[4*ii];
          efv[4*ii+1] = t.y + xs[4*ii+1];
          efv[4*ii+2] = t.z + xs[4*ii+2];
          efv[4*ii+3] = t.w + xs[4*ii+3];
        }
      }
      if (MODE == 1 || MODE == 2) {
        float4* efp = (float4*)(ef + (size_t)i * 16);
#pragma unroll
        for (int ii = 0; ii < 4; ii++)
          efp[ii] = make_float4(efv[4*ii], efv[4*ii+1], efv[4*ii+2], efv[4*ii+3]);
      }
#pragma unroll
      for (int m = 0; m < 32; m++) {
        float a = B1[m];
#pragma unroll
        for (int ii = 0; ii < 16; ii++) a += efv[ii] * W1[ii * 32 + m];
        h1[m] = fmaxf(a, 0.f);
      }
    }
#pragma unroll
    for (int m = 0; m < 32; m++) {
      float a = B2[m];
#pragma unroll
      for (int k = 0; k < 32; k++) a += h1[k] * W2[k * 32 + m];
      h2[m] = fmaxf(a, 0.f);
    }
  }

  float bsc = F_Y0 * scaleP[i];

  // kv[o] = bsc * (B3[o,:] + sum_m h2[m] W3[m,o,:]) . xs   (runtime o-loop)
#pragma unroll 1
  for (int o = 0; o < 16; ++o) {
    float a = 0.f;
#pragma unroll
    for (int ii = 0; ii < 16; ii++) a += B3[o * 16 + ii] * xs[ii];
#pragma unroll
    for (int m = 0; m < 32; m++) {
      float t = 0.f;
#pragma unroll
      for (int ii = 0; ii < 16; ii++) t += W3[m * 256 + o * 16 + ii] * xs[ii];
      a += h2[m] * t;
    }
    kvT[(size_t)o * E + i] = a * bsc;
  }
}

// ---------------- fused softmax + aggregation gather: one thread per (node, head) ----------------
// agg[n,h] = sum_j w*val / max(sum_j w, 1e-20),  w = scale[j]*exp(key[j,h]*q[n,h])
__global__ __launch_bounds__(256) void k_gather_agg(
    const int* __restrict__ row_ptr, const float* __restrict__ scaleP,
    const float* __restrict__ kvT, const float* __restrict__ q,
    float* __restrict__ agg, int N, int E)
{
  int t = blockIdx.x * 256 + threadIdx.x;
  if (t >= N * 8) return;
  int n = t >> 3;
  int h = t & 7;
  float qh = q[t];
  int j0 = row_ptr[n], j1 = row_ptr[n + 1];
  const float* keyrow = kvT + (size_t)(8 + h) * E;
  const float* valrow = kvT + (size_t)h * E;
  float num = 0.f, den = 0.f;
  for (int j = j0; j < j1; ++j) {
    float lg = fminf(keyrow[j] * qh, 60.0f);   // max-subtraction cancels; clamp for overflow safety
    float w = scaleP[j] * expf(lg);
    num += w * valrow[j];
    den += w;
  }
  agg[t] = num / fmaxf(den, 1e-20f);
}

// ---------------- feats gather: one thread per (node, o) ----------------
__global__ __launch_bounds__(256) void k_gather_feats(
    const int* __restrict__ row_ptr, const float* __restrict__ kvT,
    float* __restrict__ feats, int N, int E)
{
  int t = blockIdx.x * 256 + threadIdx.x;
  if (t >= N * 16) return;
  int n = t >> 4;
  int o = t & 15;
  int j0 = row_ptr[n], j1 = row_ptr[n + 1];
  const float* row = kvT + (size_t)o * E;
  float a = 0.f;
  for (int j = j0; j < j1; ++j) a += row[j];
  feats[t] = a;
}

// ---------------- node update: x_out = [agg, x_in] @ Wproj^T ; q = x_out @ Wq_next^T ----------------
__global__ __launch_bounds__(256) void k_node_update(
    const float* __restrict__ agg, const float* __restrict__ xin,
    const float* __restrict__ Wproj, const float* __restrict__ Wq_next,
    float* __restrict__ xout, float* __restrict__ q, int N)
{
  int n = blockIdx.x * 256 + threadIdx.x;
  if (n >= N) return;
  float cat[24];
  load8(agg + (size_t)n * 8, cat);
  load16(xin + (size_t)n * 16, cat + 8);
  float xn[16];
#pragma unroll
  for (int o = 0; o < 16; o++) {
    float a = 0.f;
#pragma unroll
    for (int j = 0; j < 24; j++) a += Wproj[o * 24 + j] * cat[j];
    xn[o] = a;
  }
  store16(xout + (size_t)n * 16, xn);
  float qv[8];
#pragma unroll
  for (int h = 0; h < 8; h++) {
    float a = 0.f;
#pragma unroll
    for (int i = 0; i < 16; i++) a += Wq_next[h * 16 + i] * xn[i];
    qv[h] = a;
  }
  store8(q + (size_t)n * 8, qv);
}

// ---------------- final node MLP + energy reduction ----------------
__global__ __launch_bounds__(256) void k_node_final(
    const float* __restrict__ x, const float* __restrict__ semb,
    const float* __restrict__ feats, const float* __restrict__ Wself,
    const float* __restrict__ mW1, const float* __restrict__ mb1,
    const float* __restrict__ mW2, const float* __restrict__ mb2,
    const float* __restrict__ mW3, const float* __restrict__ mb3,
    float* __restrict__ out, int N)
{
  int n = blockIdx.x * 256 + threadIdx.x;
  float learned = 0.f;
  if (n < N) {
    float xv[16], ft[16], sb[16];
    load16(x + (size_t)n * 16, xv);
    load16(feats + (size_t)n * 16, ft);
    load16(semb + (size_t)n * 16, sb);
    float cat[32];
#pragma unroll
    for (int i = 0; i < 16; i++) cat[i] = sb[i];
#pragma unroll
    for (int o = 0; o < 16; o++) {
      float a = ft[o];
#pragma unroll
      for (int i = 0; i < 16; i++) a += Wself[o * 16 + i] * xv[i];
      cat[16 + o] = a;
    }
    float hh[16];
#pragma unroll
    for (int j = 0; j < 16; j++) {
      float a = mb1[j];
#pragma unroll
      for (int k = 0; k < 32; k++) a += cat[k] * mW1[k * 16 + j];
      hh[j] = siluf(a);
    }
    float h2[16];
#pragma unroll
    for (int j = 0; j < 16; j++) {
      float a = mb2[j];
#pragma unroll
      for (int k = 0; k < 16; k++) a += hh[k] * mW2[k * 16 + j];
      h2[j] = siluf(a);
    }
    float a = mb3[0];
#pragma unroll
    for (int k = 0; k < 16; k++) a += h2[k] * mW3[k];
    learned = a;
  }
#pragma unroll
  for (int off = 32; off > 0; off >>= 1) learned += __shfl_down(learned, off, 64);
  if ((threadIdx.x & 63) == 0) atomicAdd(out, learned);
}

extern "C" void kernel_launch(void* const* d_in, const int* in_sizes, int n_in,
                              void* d_out, int out_size, void* d_ws, size_t ws_size,
                              hipStream_t stream)
{
  const int*   species = (const int*)d_in[0];
  const int*   src     = (const int*)d_in[1];
  const int*   dst     = (const int*)d_in[2];
  const float* rel_pos = (const float*)d_in[3];
  const float* emb     = (const float*)d_in[4];
  const float* kv_W1   = (const float*)d_in[5];
  const float* kv_b1   = (const float*)d_in[6];
  const float* kv_W2   = (const float*)d_in[7];
  const float* kv_b2   = (const float*)d_in[8];
  const float* kv_W3   = (const float*)d_in[9];
  const float* kv_b3   = (const float*)d_in[10];
  const float* Wq      = (const float*)d_in[11];
  const float* Wproj   = (const float*)d_in[12];
  const float* fin_W1  = (const float*)d_in[13];
  const float* fin_b1  = (const float*)d_in[14];
  const float* fin_W2  = (const float*)d_in[15];
  const float* fin_b2  = (const float*)d_in[16];
  const float* fin_W3  = (const float*)d_in[17];
  const float* fin_b3  = (const float*)d_in[18];
  const float* Wself   = (const float*)d_in[19];
  const float* mlp_W1  = (const float*)d_in[20];
  const float* mlp_b1  = (const float*)d_in[21];
  const float* mlp_W2  = (const float*)d_in[22];
  const float* mlp_b2  = (const float*)d_in[23];
  const float* mlp_W3  = (const float*)d_in[24];
  const float* mlp_b3  = (const float*)d_in[25];

  const int N = in_sizes[0];
  const int E = in_sizes[1];

  char* p = (char*)d_ws;
  auto alloc = [&](size_t bytes) -> void* {
    void* r = (void*)p;
    p += (bytes + 255) & ~(size_t)255;
    return r;
  };
  float* dist_   = (float*)alloc((size_t)E * 4);
  float* scale_  = (float*)alloc((size_t)E * 4);
  float* distP   = (float*)alloc((size_t)E * 4);
  float* scaleP  = (float*)alloc((size_t)E * 4);
  int*   srcP    = (int*)  alloc((size_t)E * 4);
  float* ef      = (float*)alloc((size_t)E * 16 * 4);
  float* kvT     = (float*)alloc((size_t)E * 16 * 4);
  float* xA      = (float*)alloc((size_t)N * 16 * 4);
  float* xB      = (float*)alloc((size_t)N * 16 * 4);
  float* q       = (float*)alloc((size_t)N * 8 * 4);
  float* semb    = (float*)alloc((size_t)N * 16 * 4);
  float* agg     = (float*)alloc((size_t)N * 8 * 4);
  float* feats   = (float*)alloc((size_t)N * 16 * 4);
  int*   cnt     = (int*)  alloc((size_t)N * 4);
  int*   row_ptr = (int*)  alloc((size_t)(N + 1) * 4);
  int*   row_cur = (int*)  alloc((size_t)N * 4);
  int*   bsum    = (int*)  alloc(128 * 4);
  int*   boff    = (int*)  alloc(128 * 4);

  dim3 blk(256);
  dim3 egrid((E + 255) / 256);
  dim3 ngrid((N + 255) / 256);      // 128 blocks (N=32768)
  dim3 n8grid((N * 8 + 255) / 256);
  dim3 n16grid((N * 16 + 255) / 256);

  hipMemsetAsync(d_out, 0, sizeof(float), stream);
  hipMemsetAsync(cnt, 0, (size_t)N * 4, stream);

  k_pre<<<egrid, blk, 0, stream>>>(species, src, dst, rel_pos, dist_, scale_,
                                   (float*)d_out, E);
  // CSR build (once; dst is fixed across layers)
  k_hist<<<egrid, blk, 0, stream>>>(dst, cnt, E);
  k_scan1<<<ngrid, blk, 0, stream>>>(cnt, row_ptr, bsum);
  k_scan2<<<dim3(1), dim3(128), 0, stream>>>(bsum, boff);
  k_scan3<<<ngrid, blk, 0, stream>>>(row_ptr, row_cur, boff, N, E);
  k_scatter<<<egrid, blk, 0, stream>>>(src, dst, dist_, scale_, row_cur,
                                       srcP, distP, scaleP, E);

  k_node_init<<<ngrid, blk, 0, stream>>>(species, emb, Wq, xA, semb, q, N);

  float* xin = xA;
  float* xout = xB;
  for (int l = 0; l < 4; l++) {
    const float* W1 = kv_W1 + (size_t)l * 16 * 32;
    const float* B1 = kv_b1 + (size_t)l * 32;
    const float* W2 = kv_W2 + (size_t)l * 32 * 32;
    const float* B2 = kv_b2 + (size_t)l * 32;
    const float* W3 = kv_W3 + (size_t)l * 32 * 256;
    const float* B3 = kv_b3 + (size_t)l * 256;
    const float* Wqn = Wq + (size_t)((l < 3) ? (l + 1) : 0) * 8 * 16;
    if (l == 0) {
      k_edge_conv<0><<<egrid, blk, 0, stream>>>(srcP, scaleP, distP, ef, xin,
                                                W1, B1, W2, B2, W3, B3, kvT, E);
    } else if (l == 1) {
      k_edge_conv<1><<<egrid, blk, 0, stream>>>(srcP, scaleP, distP, ef, xin,
                                                W1, B1, W2, B2, W3, B3, kvT, E);
    } else {
      k_edge_conv<2><<<egrid, blk, 0, stream>>>(srcP, scaleP, distP, ef, xin,
                                                W1, B1, W2, B2, W3, B3, kvT, E);
    }
    k_gather_agg<<<n8grid, blk, 0, stream>>>(row_ptr, scaleP, kvT, q, agg, N, E);
    k_node_update<<<ngrid, blk, 0, stream>>>(agg, xin, Wproj + (size_t)l * 16 * 24, Wqn,
                                             xout, q, N);
    float* tmp = xin; xin = xout; xout = tmp;
  }

  k_edge_conv<3><<<egrid, blk, 0, stream>>>(srcP, scaleP, distP, ef, xin,
                                            fin_W1, fin_b1, fin_W2, fin_b2, fin_W3, fin_b3,
                                            kvT, E);
  k_gather_feats<<<n16grid, blk, 0, stream>>>(row_ptr, kvT, feats, N, E);
  k_node_final<<<ngrid, blk, 0, stream>>>(xin, semb, feats, Wself,
                                          mlp_W1, mlp_b1, mlp_W2, mlp_b2, mlp_W3, mlp_b3,
                                          (float*)d_out, N);
}

// Round 4
// 1073.149 us; speedup vs baseline: 3.7390x; 1.7872x over previous
//
#include <hip/hip_runtime.h>

constexpr float F_Y0     = 0.28209479177387814f;
constexpr float F_CUTOFF = 4.6f;

typedef short short8 __attribute__((ext_vector_type(8)));
typedef float f32x4  __attribute__((ext_vector_type(4)));

__device__ __forceinline__ float siluf(float v) { return v / (1.0f + expf(-v)); }

// round-to-nearest-even fp32 -> bf16 (as uint16 in low bits)
__device__ __forceinline__ unsigned bfr(float x) {
  unsigned u = __float_as_uint(x);
  return (u + 0x7fffu + ((u >> 16) & 1u)) >> 16;
}
__device__ __forceinline__ unsigned pk2(float a, float b) {
  return bfr(a) | (bfr(b) << 16);
}

union FragU { uint4 u; short8 s; };

__device__ __forceinline__ void load16(const float* p, float* r) {
  const float4* p4 = (const float4*)p;
#pragma unroll
  for (int i = 0; i < 4; i++) {
    float4 t = p4[i];
    r[4*i] = t.x; r[4*i+1] = t.y; r[4*i+2] = t.z; r[4*i+3] = t.w;
  }
}
__device__ __forceinline__ void store16(float* p, const float* r) {
  float4* p4 = (float4*)p;
#pragma unroll
  for (int i = 0; i < 4; i++) p4[i] = make_float4(r[4*i], r[4*i+1], r[4*i+2], r[4*i+3]);
}
__device__ __forceinline__ void load8(const float* p, float* r) {
  const float4* p4 = (const float4*)p;
#pragma unroll
  for (int i = 0; i < 2; i++) {
    float4 t = p4[i];
    r[4*i] = t.x; r[4*i+1] = t.y; r[4*i+2] = t.z; r[4*i+3] = t.w;
  }
}
__device__ __forceinline__ void store8(float* p, const float* r) {
  float4* p4 = (float4*)p;
#pragma unroll
  for (int i = 0; i < 2; i++) p4[i] = make_float4(r[4*i], r[4*i+1], r[4*i+2], r[4*i+3]);
}

// ---------------- per-edge precompute: dist, scale, Coulomb sum ----------------
__global__ __launch_bounds__(256) void k_pre(
    const int* __restrict__ species, const int* __restrict__ src, const int* __restrict__ dst,
    const float* __restrict__ rel_pos,
    float* __restrict__ dist_, float* __restrict__ scale_,
    float* __restrict__ out, int E)
{
  int e = blockIdx.x * 256 + threadIdx.x;
  float ce = 0.0f;
  if (e < E) {
    float px = rel_pos[3*(size_t)e + 0];
    float py = rel_pos[3*(size_t)e + 1];
    float pz = rel_pos[3*(size_t)e + 2];
    float dist = sqrtf(px*px + py*py + pz*pz);
    float xc = dist * (1.0f / F_CUTOFF);
    bool in_cut = dist < F_CUTOFF;
    float x2 = in_cut ? xc * xc : 0.0f;
    x2 = fminf(x2, 1.0f - 1e-6f);
    float sc = in_cut ? expf(3.0f - 3.0f / (1.0f - x2)) : 0.0f;
    dist_[e] = dist;
    scale_[e] = sc;
    float Zu = (float)species[src[e]];
    float Zv = (float)species[dst[e]];
    float raw = 0.529f * Zu * Zv / (2.0f * dist);
    float au = 0.8854f * 0.529f / (powf(Zu, 0.23f) + powf(Zv, 0.23f));
    float xx = dist / au;
    float screen = 0.1818f   * expf(-3.2f    * xx)
                 + 0.5099f   * expf(-0.9423f * xx)
                 + 0.2802f   * expf(-0.4028f * xx)
                 + 0.02817f  * expf(-0.2016f * xx);
    ce = raw * screen * sc;
  }
#pragma unroll
  for (int off = 32; off > 0; off >>= 1) ce += __shfl_down(ce, off, 64);
  if ((threadIdx.x & 63) == 0) atomicAdd(out, ce);
}

// ---------------- CSR build ----------------
__global__ __launch_bounds__(256) void k_hist(
    const int* __restrict__ dst, int* __restrict__ cnt, int E)
{
  int e = blockIdx.x * 256 + threadIdx.x;
  if (e < E) atomicAdd(&cnt[dst[e]], 1);
}

__global__ __launch_bounds__(256) void k_scan1(
    const int* __restrict__ cnt, int* __restrict__ row_ptr, int* __restrict__ bsum)
{
  __shared__ int s[256];
  int tid = threadIdx.x;
  int n = blockIdx.x * 256 + tid;
  int v = cnt[n];
  s[tid] = v;
  __syncthreads();
#pragma unroll
  for (int off = 1; off < 256; off <<= 1) {
    int t = (tid >= off) ? s[tid - off] : 0;
    __syncthreads();
    s[tid] += t;
    __syncthreads();
  }
  row_ptr[n] = s[tid] - v;
  if (tid == 255) bsum[blockIdx.x] = s[255];
}

__global__ __launch_bounds__(128) void k_scan2(int* __restrict__ bsum, int* __restrict__ boff)
{
  __shared__ int s[128];
  int tid = threadIdx.x;
  int v = bsum[tid];
  s[tid] = v;
  __syncthreads();
#pragma unroll
  for (int off = 1; off < 128; off <<= 1) {
    int t = (tid >= off) ? s[tid - off] : 0;
    __syncthreads();
    s[tid] += t;
    __syncthreads();
  }
  boff[tid] = s[tid] - v;
}

__global__ __launch_bounds__(256) void k_scan3(
    int* __restrict__ row_ptr, int* __restrict__ row_cur,
    const int* __restrict__ boff, int N, int E)
{
  int n = blockIdx.x * 256 + threadIdx.x;
  int rp = row_ptr[n] + boff[blockIdx.x];
  row_ptr[n] = rp;
  row_cur[n] = rp;
  if (n == 0) row_ptr[N] = E;
}

__global__ __launch_bounds__(256) void k_scatter(
    const int* __restrict__ src, const int* __restrict__ dst,
    const float* __restrict__ dist_, const float* __restrict__ scale_,
    int* __restrict__ row_cur,
    int* __restrict__ srcP, float* __restrict__ distP, float* __restrict__ scaleP, int E)
{
  int e = blockIdx.x * 256 + threadIdx.x;
  if (e >= E) return;
  int d = dst[e];
  int pos = atomicAdd(&row_cur[d], 1);
  srcP[pos] = src[e];
  distP[pos] = dist_[e];
  scaleP[pos] = scale_[e];
}

// ---------------- W3/B3 -> bf16 B-fragment prepack ----------------
// Fragment f (0..15): half h=f>>3, step s=f&7; covers K-chunk of the 512-wide
// (m,i) outer-product dimension. f==16: bias block (m'=0 -> B3, m'=1 -> zero).
// Lane l: n=o=l&15, k=(l>>4)*8+j. Stored as uint4 per (f,lane).
__global__ __launch_bounds__(256) void k_prepack(
    const float* __restrict__ kv_W3, const float* __restrict__ kv_b3,
    const float* __restrict__ fin_W3, const float* __restrict__ fin_b3,
    uint4* __restrict__ WF)
{
  int t = blockIdx.x * 256 + threadIdx.x;
  if (t >= 5 * 17 * 64) return;
  int lyr = t / (17 * 64);
  int rem = t - lyr * 17 * 64;
  int f = rem >> 6;
  int l = rem & 63;
  int q = l >> 4;
  int o = l & 15;
  const float* W3 = (lyr < 4) ? (kv_W3 + (size_t)lyr * 32 * 256) : fin_W3;
  const float* B3 = (lyr < 4) ? (kv_b3 + (size_t)lyr * 256) : fin_b3;
  float v[8];
#pragma unroll
  for (int j = 0; j < 8; j++) {
    if (f < 16) {
      int h = f >> 3, s = f & 7;
      int kl = s * 32 + q * 8 + j;         // within half
      int m = h * 16 + (kl >> 4);
      int i = kl & 15;
      v[j] = W3[m * 256 + o * 16 + i];
    } else {
      int kl = q * 8 + j;
      int mp = kl >> 4;
      int i = kl & 15;
      v[j] = mp ? 0.0f : B3[o * 16 + i];
    }
  }
  uint4 dw;
  dw.x = pk2(v[0], v[1]);
  dw.y = pk2(v[2], v[3]);
  dw.z = pk2(v[4], v[5]);
  dw.w = pk2(v[6], v[7]);
  WF[t] = dw;
}

// ---------------- node init ----------------
__global__ __launch_bounds__(256) void k_node_init(
    const int* __restrict__ species, const float* __restrict__ emb,
    const float* __restrict__ Wq0,
    float* __restrict__ x, float* __restrict__ semb, float* __restrict__ q, int N)
{
  int n = blockIdx.x * 256 + threadIdx.x;
  if (n >= N) return;
  int sp = species[n] - 1;
  float xv[16];
  load16(emb + (size_t)sp * 16, xv);
  store16(x + (size_t)n * 16, xv);
  store16(semb + (size_t)n * 16, xv);
  float qv[8];
#pragma unroll
  for (int h = 0; h < 8; h++) {
    float a = 0.f;
#pragma unroll
    for (int i = 0; i < 16; i++) a += Wq0[h * 16 + i] * xv[i];
    qv[h] = a;
  }
  store8(q + (size_t)n * 8, qv);
}

// ---------------- heavy edge conv: MFMA over P = h2 (x) xs ----------------
// Block = 64 edges, 256 threads (4 waves). Wave w computes h2 rows
// {w*4..w*4+3} and {16+w*4..}, builds its P chunk in LDS (bf16, k-major,
// pairs packed in dwords, row stride 65 dwords), then wave g handles the
// 16-edge MFMA tile g: D[e][o] = P @ W3' accumulated over K=544
// (512 outer-product + 32 bias block). D-layout IS kv: o=lane&15,
// e=quad*4+reg. 4 scalar stores/lane to kvT.
// MODE 0: layer 0 (h1 from dist only). MODE 1: ef=xs+dist, store.
// MODE 2: ef load+add+store. MODE 3: ef load+add, no store.
template <int MODE>
__global__ __launch_bounds__(256, 4) void k_edge_conv(
    const int* __restrict__ srcP,
    const float* __restrict__ scaleP, const float* __restrict__ distP,
    float* __restrict__ ef, const float* __restrict__ x,
    const float* __restrict__ W1, const float* __restrict__ B1,
    const float* __restrict__ W2, const float* __restrict__ B2,
    const uint4* __restrict__ WF,
    float* __restrict__ kvT, int E)
{
  __shared__ unsigned P[144 * 65];

  int tid = threadIdx.x;
  int w = __builtin_amdgcn_readfirstlane(tid >> 6);  // wave id, SGPR
  int l = tid & 63;
  int q = l >> 4;
  int lo = l & 15;
  int el = blockIdx.x * 64 + l;

  // ---- phase A: per-thread (lane=edge), per-wave weight rows ----
  float xs[16];
  load16(x + (size_t)srcP[el] * 16, xs);

  float h1[32];
  if (MODE == 0) {
    float dd = distP[el];
#pragma unroll
    for (int m = 0; m < 32; m++) h1[m] = fmaxf(B1[m] + dd * W1[15 * 32 + m], 0.f);
  } else {
    float efv[16];
    if (MODE == 1) {
#pragma unroll
      for (int i = 0; i < 16; i++) efv[i] = xs[i];
      efv[15] += distP[el];
    } else {
      const float4* efp = (const float4*)(ef + (size_t)el * 16);
#pragma unroll
      for (int i = 0; i < 4; i++) {
        float4 t = efp[i];
        efv[4*i]   = t.x + xs[4*i];
        efv[4*i+1] = t.y + xs[4*i+1];
        efv[4*i+2] = t.z + xs[4*i+2];
        efv[4*i+3] = t.w + xs[4*i+3];
      }
    }
    if (MODE == 1 || MODE == 2) {
      // each wave stores its quarter of the new ef
      ((float4*)(ef + (size_t)el * 16))[w] =
          make_float4(efv[4*w], efv[4*w+1], efv[4*w+2], efv[4*w+3]);
    }
#pragma unroll
    for (int m = 0; m < 32; m++) {
      float a = B1[m];
#pragma unroll
      for (int i = 0; i < 16; i++) a += efv[i] * W1[i * 32 + m];
      h1[m] = fmaxf(a, 0.f);
    }
  }

  float h2v[8];
#pragma unroll
  for (int jj = 0; jj < 8; jj++) {
    int m = ((jj >> 2) << 4) + w * 4 + (jj & 3);   // SGPR index
    float a = B2[m];
#pragma unroll
    for (int k = 0; k < 32; k++) a += h1[k] * W2[k * 32 + m];
    h2v[jj] = fmaxf(a, 0.f);
  }

  // ---- load B-fragments (17 x uint4 per lane) ----
  uint4 wfv[17];
#pragma unroll
  for (int f = 0; f < 17; f++) wfv[f] = WF[f * 64 + l];

  // ---- build P half 0 (+ static bias rows) ----
#pragma unroll
  for (int jj = 0; jj < 4; jj++) {
    int rowb = (w * 4 + jj) * 8;
    float hm = h2v[jj];
#pragma unroll
    for (int id = 0; id < 8; id++)
      P[(rowb + id) * 65 + l] = pk2(hm * xs[2*id], hm * xs[2*id+1]);
  }
  if (w == 0) {
#pragma unroll
    for (int id = 0; id < 8; id++)
      P[(128 + id) * 65 + l] = pk2(xs[2*id], xs[2*id+1]);
  }
  if (w == 1) {
#pragma unroll
    for (int id = 0; id < 8; id++)
      P[(136 + id) * 65 + l] = 0u;
  }
  __syncthreads();

  // ---- MFMA half 0 ----
  f32x4 acc = {0.f, 0.f, 0.f, 0.f};
  int acol = w * 16 + lo;
#pragma unroll
  for (int s = 0; s < 8; s++) {
    FragU a;
    a.u.x = P[(s * 16 + q * 4 + 0) * 65 + acol];
    a.u.y = P[(s * 16 + q * 4 + 1) * 65 + acol];
    a.u.z = P[(s * 16 + q * 4 + 2) * 65 + acol];
    a.u.w = P[(s * 16 + q * 4 + 3) * 65 + acol];
    FragU b; b.u = wfv[s];
    acc = __builtin_amdgcn_mfma_f32_16x16x32_bf16(a.s, b.s, acc, 0, 0, 0);
  }
  __syncthreads();

  // ---- build P half 1 ----
#pragma unroll
  for (int jj = 0; jj < 4; jj++) {
    int rowb = (w * 4 + jj) * 8;
    float hm = h2v[4 + jj];
#pragma unroll
    for (int id = 0; id < 8; id++)
      P[(rowb + id) * 65 + l] = pk2(hm * xs[2*id], hm * xs[2*id+1]);
  }
  __syncthreads();

  // ---- MFMA half 1 + bias block ----
#pragma unroll
  for (int s = 0; s < 8; s++) {
    FragU a;
    a.u.x = P[(s * 16 + q * 4 + 0) * 65 + acol];
    a.u.y = P[(s * 16 + q * 4 + 1) * 65 + acol];
    a.u.z = P[(s * 16 + q * 4 + 2) * 65 + acol];
    a.u.w = P[(s * 16 + q * 4 + 3) * 65 + acol];
    FragU b; b.u = wfv[8 + s];
    acc = __builtin_amdgcn_mfma_f32_16x16x32_bf16(a.s, b.s, acc, 0, 0, 0);
  }
  {
    FragU a;
    a.u.x = P[(128 + q * 4 + 0) * 65 + acol];
    a.u.y = P[(128 + q * 4 + 1) * 65 + acol];
    a.u.z = P[(128 + q * 4 + 2) * 65 + acol];
    a.u.w = P[(128 + q * 4 + 3) * 65 + acol];
    FragU b; b.u = wfv[16];
    acc = __builtin_amdgcn_mfma_f32_16x16x32_bf16(a.s, b.s, acc, 0, 0, 0);
  }

  // ---- epilogue: kv[e][o] = acc * bscale ----
#pragma unroll
  for (int r = 0; r < 4; r++) {
    int ee = blockIdx.x * 64 + w * 16 + q * 4 + r;
    float bsc = F_Y0 * scaleP[ee];
    kvT[(size_t)lo * E + ee] = acc[r] * bsc;
  }
}

// ---------------- fused softmax + aggregation gather ----------------
__global__ __launch_bounds__(256) void k_gather_agg(
    const int* __restrict__ row_ptr, const float* __restrict__ scaleP,
    const float* __restrict__ kvT, const float* __restrict__ q,
    float* __restrict__ agg, int N, int E)
{
  int t = blockIdx.x * 256 + threadIdx.x;
  if (t >= N * 8) return;
  int n = t >> 3;
  int h = t & 7;
  float qh = q[t];
  int j0 = row_ptr[n], j1 = row_ptr[n + 1];
  const float* keyrow = kvT + (size_t)(8 + h) * E;
  const float* valrow = kvT + (size_t)h * E;
  float num = 0.f, den = 0.f;
  for (int j = j0; j < j1; ++j) {
    float lg = fminf(keyrow[j] * qh, 60.0f);
    float w = scaleP[j] * expf(lg);
    num += w * valrow[j];
    den += w;
  }
  agg[t] = num / fmaxf(den, 1e-20f);
}

// ---------------- feats gather ----------------
__global__ __launch_bounds__(256) void k_gather_feats(
    const int* __restrict__ row_ptr, const float* __restrict__ kvT,
    float* __restrict__ feats, int N, int E)
{
  int t = blockIdx.x * 256 + threadIdx.x;
  if (t >= N * 16) return;
  int n = t >> 4;
  int o = t & 15;
  int j0 = row_ptr[n], j1 = row_ptr[n + 1];
  const float* row = kvT + (size_t)o * E;
  float a = 0.f;
  for (int j = j0; j < j1; ++j) a += row[j];
  feats[t] = a;
}

// ---------------- node update ----------------
__global__ __launch_bounds__(256) void k_node_update(
    const float* __restrict__ agg, const float* __restrict__ xin,
    const float* __restrict__ Wproj, const float* __restrict__ Wq_next,
    float* __restrict__ xout, float* __restrict__ q, int N)
{
  int n = blockIdx.x * 256 + threadIdx.x;
  if (n >= N) return;
  float cat[24];
  load8(agg + (size_t)n * 8, cat);
  load16(xin + (size_t)n * 16, cat + 8);
  float xn[16];
#pragma unroll
  for (int o = 0; o < 16; o++) {
    float a = 0.f;
#pragma unroll
    for (int j = 0; j < 24; j++) a += Wproj[o * 24 + j] * cat[j];
    xn[o] = a;
  }
  store16(xout + (size_t)n * 16, xn);
  float qv[8];
#pragma unroll
  for (int h = 0; h < 8; h++) {
    float a = 0.f;
#pragma unroll
    for (int i = 0; i < 16; i++) a += Wq_next[h * 16 + i] * xn[i];
    qv[h] = a;
  }
  store8(q + (size_t)n * 8, qv);
}

// ---------------- final node MLP + energy reduction ----------------
__global__ __launch_bounds__(256) void k_node_final(
    const float* __restrict__ x, const float* __restrict__ semb,
    const float* __restrict__ feats, const float* __restrict__ Wself,
    const float* __restrict__ mW1, const float* __restrict__ mb1,
    const float* __restrict__ mW2, const float* __restrict__ mb2,
    const float* __restrict__ mW3, const float* __restrict__ mb3,
    float* __restrict__ out, int N)
{
  int n = blockIdx.x * 256 + threadIdx.x;
  float learned = 0.f;
  if (n < N) {
    float xv[16], ft[16], sb[16];
    load16(x + (size_t)n * 16, xv);
    load16(feats + (size_t)n * 16, ft);
    load16(semb + (size_t)n * 16, sb);
    float cat[32];
#pragma unroll
    for (int i = 0; i < 16; i++) cat[i] = sb[i];
#pragma unroll
    for (int o = 0; o < 16; o++) {
      float a = ft[o];
#pragma unroll
      for (int i = 0; i < 16; i++) a += Wself[o * 16 + i] * xv[i];
      cat[16 + o] = a;
    }
    float hh[16];
#pragma unroll
    for (int j = 0; j < 16; j++) {
      float a = mb1[j];
#pragma unroll
      for (int k = 0; k < 32; k++) a += cat[k] * mW1[k * 16 + j];
      hh[j] = siluf(a);
    }
    float h2[16];
#pragma unroll
    for (int j = 0; j < 16; j++) {
      float a = mb2[j];
#pragma unroll
      for (int k = 0; k < 16; k++) a += hh[k] * mW2[k * 16 + j];
      h2[j] = siluf(a);
    }
    float a = mb3[0];
#pragma unroll
    for (int k = 0; k < 16; k++) a += h2[k] * mW3[k];
    learned = a;
  }
#pragma unroll
  for (int off = 32; off > 0; off >>= 1) learned += __shfl_down(learned, off, 64);
  if ((threadIdx.x & 63) == 0) atomicAdd(out, learned);
}

extern "C" void kernel_launch(void* const* d_in, const int* in_sizes, int n_in,
                              void* d_out, int out_size, void* d_ws, size_t ws_size,
                              hipStream_t stream)
{
  const int*   species = (const int*)d_in[0];
  const int*   src     = (const int*)d_in[1];
  const int*   dst     = (const int*)d_in[2];
  const float* rel_pos = (const float*)d_in[3];
  const float* emb     = (const float*)d_in[4];
  const float* kv_W1   = (const float*)d_in[5];
  const float* kv_b1   = (const float*)d_in[6];
  const float* kv_W2   = (const float*)d_in[7];
  const float* kv_b2   = (const float*)d_in[8];
  const float* kv_W3   = (const float*)d_in[9];
  const float* kv_b3   = (const float*)d_in[10];
  const float* Wq      = (const float*)d_in[11];
  const float* Wproj   = (const float*)d_in[12];
  const float* fin_W1  = (const float*)d_in[13];
  const float* fin_b1  = (const float*)d_in[14];
  const float* fin_W2  = (const float*)d_in[15];
  const float* fin_b2  = (const float*)d_in[16];
  const float* fin_W3  = (const float*)d_in[17];
  const float* fin_b3  = (const float*)d_in[18];
  const float* Wself   = (const float*)d_in[19];
  const float* mlp_W1  = (const float*)d_in[20];
  const float* mlp_b1  = (const float*)d_in[21];
  const float* mlp_W2  = (const float*)d_in[22];
  const float* mlp_b2  = (const float*)d_in[23];
  const float* mlp_W3  = (const float*)d_in[24];
  const float* mlp_b3  = (const float*)d_in[25];

  const int N = in_sizes[0];
  const int E = in_sizes[1];

  char* p = (char*)d_ws;
  auto alloc = [&](size_t bytes) -> void* {
    void* r = (void*)p;
    p += (bytes + 255) & ~(size_t)255;
    return r;
  };
  float* dist_   = (float*)alloc((size_t)E * 4);
  float* scale_  = (float*)alloc((size_t)E * 4);
  float* distP   = (float*)alloc((size_t)E * 4);
  float* scaleP  = (float*)alloc((size_t)E * 4);
  int*   srcP    = (int*)  alloc((size_t)E * 4);
  float* ef      = (float*)alloc((size_t)E * 16 * 4);
  float* kvT     = (float*)alloc((size_t)E * 16 * 4);
  float* xA      = (float*)alloc((size_t)N * 16 * 4);
  float* xB      = (float*)alloc((size_t)N * 16 * 4);
  float* q       = (float*)alloc((size_t)N * 8 * 4);
  float* semb    = (float*)alloc((size_t)N * 16 * 4);
  float* agg     = (float*)alloc((size_t)N * 8 * 4);
  float* feats   = (float*)alloc((size_t)N * 16 * 4);
  int*   cnt     = (int*)  alloc((size_t)N * 4);
  int*   row_ptr = (int*)  alloc((size_t)(N + 1) * 4);
  int*   row_cur = (int*)  alloc((size_t)N * 4);
  int*   bsum    = (int*)  alloc(128 * 4);
  int*   boff    = (int*)  alloc(128 * 4);
  uint4* WF      = (uint4*)alloc((size_t)5 * 17 * 64 * 16);

  dim3 blk(256);
  dim3 egrid((E + 255) / 256);
  dim3 cgrid(E / 64);               // E=524288 -> 8192 blocks, 64 edges each
  dim3 ngrid((N + 255) / 256);
  dim3 n8grid((N * 8 + 255) / 256);
  dim3 n16grid((N * 16 + 255) / 256);

  hipMemsetAsync(d_out, 0, sizeof(float), stream);
  hipMemsetAsync(cnt, 0, (size_t)N * 4, stream);

  k_prepack<<<dim3(22), blk, 0, stream>>>(kv_W3, kv_b3, fin_W3, fin_b3, WF);

  k_pre<<<egrid, blk, 0, stream>>>(species, src, dst, rel_pos, dist_, scale_,
                                   (float*)d_out, E);
  k_hist<<<egrid, blk, 0, stream>>>(dst, cnt, E);
  k_scan1<<<ngrid, blk, 0, stream>>>(cnt, row_ptr, bsum);
  k_scan2<<<dim3(1), dim3(128), 0, stream>>>(bsum, boff);
  k_scan3<<<ngrid, blk, 0, stream>>>(row_ptr, row_cur, boff, N, E);
  k_scatter<<<egrid, blk, 0, stream>>>(src, dst, dist_, scale_, row_cur,
                                       srcP, distP, scaleP, E);

  k_node_init<<<ngrid, blk, 0, stream>>>(species, emb, Wq, xA, semb, q, N);

  float* xin = xA;
  float* xout = xB;
  for (int l = 0; l < 4; l++) {
    const float* W1 = kv_W1 + (size_t)l * 16 * 32;
    const float* B1 = kv_b1 + (size_t)l * 32;
    const float* W2 = kv_W2 + (size_t)l * 32 * 32;
    const float* B2 = kv_b2 + (size_t)l * 32;
    const uint4* WFl = WF + (size_t)l * 17 * 64;
    const float* Wqn = Wq + (size_t)((l < 3) ? (l + 1) : 0) * 8 * 16;
    if (l == 0) {
      k_edge_conv<0><<<cgrid, blk, 0, stream>>>(srcP, scaleP, distP, ef, xin,
                                                W1, B1, W2, B2, WFl, kvT, E);
    } else if (l == 1) {
      k_edge_conv<1><<<cgrid, blk, 0, stream>>>(srcP, scaleP, distP, ef, xin,
                                                W1, B1, W2, B2, WFl, kvT, E);
    } else {
      k_edge_conv<2><<<cgrid, blk, 0, stream>>>(srcP, scaleP, distP, ef, xin,
                                                W1, B1, W2, B2, WFl, kvT, E);
    }
    k_gather_agg<<<n8grid, blk, 0, stream>>>(row_ptr, scaleP, kvT, q, agg, N, E);
    k_node_update<<<ngrid, blk, 0, stream>>>(agg, xin, Wproj + (size_t)l * 16 * 24, Wqn,
                                             xout, q, N);
    float* tmp = xin; xin = xout; xout = tmp;
  }

  k_edge_conv<3><<<cgrid, blk, 0, stream>>>(srcP, scaleP, distP, ef, xin,
                                            fin_W1, fin_b1, fin_W2, fin_b2,
                                            WF + (size_t)4 * 17 * 64, kvT, E);
  k_gather_feats<<<n16grid, blk, 0, stream>>>(row_ptr, kvT, feats, N, E);
  k_node_final<<<ngrid, blk, 0, stream>>>(xin, semb, feats, Wself,
                                          mlp_W1, mlp_b1, mlp_W2, mlp_b2, mlp_W3, mlp_b3,
                                          (float*)d_out, N);
}

// Round 5
// 876.239 us; speedup vs baseline: 4.5793x; 1.2247x over previous
//
#include <hip/hip_runtime.h>

constexpr float F_Y0     = 0.28209479177387814f;
constexpr float F_CUTOFF = 4.6f;

typedef short short8 __attribute__((ext_vector_type(8)));
typedef float f32x4  __attribute__((ext_vector_type(4)));

__device__ __forceinline__ float siluf(float v) { return v / (1.0f + expf(-v)); }

// gfx950 hardware packed fp32->bf16 (RNE): lo = cvt(a), hi = cvt(b)
__device__ __forceinline__ unsigned pk2(float a, float b) {
  unsigned r;
  asm("v_cvt_pk_bf16_f32 %0, %1, %2" : "=v"(r) : "v"(a), "v"(b));
  return r;
}

union FragU { uint4 u; short8 s; };

__device__ __forceinline__ void load16(const float* p, float* r) {
  const float4* p4 = (const float4*)p;
#pragma unroll
  for (int i = 0; i < 4; i++) {
    float4 t = p4[i];
    r[4*i] = t.x; r[4*i+1] = t.y; r[4*i+2] = t.z; r[4*i+3] = t.w;
  }
}
__device__ __forceinline__ void store16(float* p, const float* r) {
  float4* p4 = (float4*)p;
#pragma unroll
  for (int i = 0; i < 4; i++) p4[i] = make_float4(r[4*i], r[4*i+1], r[4*i+2], r[4*i+3]);
}
__device__ __forceinline__ void load8(const float* p, float* r) {
  const float4* p4 = (const float4*)p;
#pragma unroll
  for (int i = 0; i < 2; i++) {
    float4 t = p4[i];
    r[4*i] = t.x; r[4*i+1] = t.y; r[4*i+2] = t.z; r[4*i+3] = t.w;
  }
}
__device__ __forceinline__ void store8(float* p, const float* r) {
  float4* p4 = (float4*)p;
#pragma unroll
  for (int i = 0; i < 2; i++) p4[i] = make_float4(r[4*i], r[4*i+1], r[4*i+2], r[4*i+3]);
}

// ---------------- per-edge precompute: dist, scale, Coulomb sum ----------------
__global__ __launch_bounds__(256) void k_pre(
    const int* __restrict__ species, const int* __restrict__ src, const int* __restrict__ dst,
    const float* __restrict__ rel_pos,
    float* __restrict__ dist_, float* __restrict__ scale_,
    float* __restrict__ out, int E)
{
  int e = blockIdx.x * 256 + threadIdx.x;
  float ce = 0.0f;
  if (e < E) {
    float px = rel_pos[3*(size_t)e + 0];
    float py = rel_pos[3*(size_t)e + 1];
    float pz = rel_pos[3*(size_t)e + 2];
    float dist = sqrtf(px*px + py*py + pz*pz);
    float xc = dist * (1.0f / F_CUTOFF);
    bool in_cut = dist < F_CUTOFF;
    float x2 = in_cut ? xc * xc : 0.0f;
    x2 = fminf(x2, 1.0f - 1e-6f);
    float sc = in_cut ? expf(3.0f - 3.0f / (1.0f - x2)) : 0.0f;
    dist_[e] = dist;
    scale_[e] = sc;
    float Zu = (float)species[src[e]];
    float Zv = (float)species[dst[e]];
    float raw = 0.529f * Zu * Zv / (2.0f * dist);
    float au = 0.8854f * 0.529f / (powf(Zu, 0.23f) + powf(Zv, 0.23f));
    float xx = dist / au;
    float screen = 0.1818f   * expf(-3.2f    * xx)
                 + 0.5099f   * expf(-0.9423f * xx)
                 + 0.2802f   * expf(-0.4028f * xx)
                 + 0.02817f  * expf(-0.2016f * xx);
    ce = raw * screen * sc;
  }
#pragma unroll
  for (int off = 32; off > 0; off >>= 1) ce += __shfl_down(ce, off, 64);
  if ((threadIdx.x & 63) == 0) atomicAdd(out, ce);
}

// ---------------- CSR build ----------------
__global__ __launch_bounds__(256) void k_hist(
    const int* __restrict__ dst, int* __restrict__ cnt, int E)
{
  int e = blockIdx.x * 256 + threadIdx.x;
  if (e < E) atomicAdd(&cnt[dst[e]], 1);
}

__global__ __launch_bounds__(256) void k_scan1(
    const int* __restrict__ cnt, int* __restrict__ row_ptr, int* __restrict__ bsum)
{
  __shared__ int s[256];
  int tid = threadIdx.x;
  int n = blockIdx.x * 256 + tid;
  int v = cnt[n];
  s[tid] = v;
  __syncthreads();
#pragma unroll
  for (int off = 1; off < 256; off <<= 1) {
    int t = (tid >= off) ? s[tid - off] : 0;
    __syncthreads();
    s[tid] += t;
    __syncthreads();
  }
  row_ptr[n] = s[tid] - v;
  if (tid == 255) bsum[blockIdx.x] = s[255];
}

__global__ __launch_bounds__(128) void k_scan2(int* __restrict__ bsum, int* __restrict__ boff)
{
  __shared__ int s[128];
  int tid = threadIdx.x;
  int v = bsum[tid];
  s[tid] = v;
  __syncthreads();
#pragma unroll
  for (int off = 1; off < 128; off <<= 1) {
    int t = (tid >= off) ? s[tid - off] : 0;
    __syncthreads();
    s[tid] += t;
    __syncthreads();
  }
  boff[tid] = s[tid] - v;
}

__global__ __launch_bounds__(256) void k_scan3(
    int* __restrict__ row_ptr, int* __restrict__ row_cur,
    const int* __restrict__ boff, int N, int E)
{
  int n = blockIdx.x * 256 + threadIdx.x;
  int rp = row_ptr[n] + boff[blockIdx.x];
  row_ptr[n] = rp;
  row_cur[n] = rp;
  if (n == 0) row_ptr[N] = E;
}

__global__ __launch_bounds__(256) void k_scatter(
    const int* __restrict__ src, const int* __restrict__ dst,
    const float* __restrict__ dist_, const float* __restrict__ scale_,
    int* __restrict__ row_cur,
    int* __restrict__ srcP, float* __restrict__ distP, float* __restrict__ scaleP, int E)
{
  int e = blockIdx.x * 256 + threadIdx.x;
  if (e >= E) return;
  int d = dst[e];
  int pos = atomicAdd(&row_cur[d], 1);
  srcP[pos] = src[e];
  distP[pos] = dist_[e];
  scaleP[pos] = scale_[e];
}

// ---------------- W3/B3 -> bf16 B-fragment prepack ----------------
// Linear K: kk = m*16 + i for m<32 (kk<512); kk 512..527 = bias (B3), 528..543 = zero.
// Fragment t (0..16) covers kk in [32t, 32t+32). Lane l: o=l&15, k-chunk=(l>>4)*8+j.
__global__ __launch_bounds__(256) void k_prepack(
    const float* __restrict__ kv_W3, const float* __restrict__ kv_b3,
    const float* __restrict__ fin_W3, const float* __restrict__ fin_b3,
    uint4* __restrict__ WF)
{
  int t = blockIdx.x * 256 + threadIdx.x;
  if (t >= 5 * 17 * 64) return;
  int lyr = t / (17 * 64);
  int rem = t - lyr * 17 * 64;
  int f = rem >> 6;
  int l = rem & 63;
  int qq = l >> 4;
  int o = l & 15;
  const float* W3 = (lyr < 4) ? (kv_W3 + (size_t)lyr * 32 * 256) : fin_W3;
  const float* B3 = (lyr < 4) ? (kv_b3 + (size_t)lyr * 256) : fin_b3;
  float v[8];
#pragma unroll
  for (int j = 0; j < 8; j++) {
    int kk = f * 32 + qq * 8 + j;
    if (kk < 512) {
      int m = kk >> 4, i = kk & 15;
      v[j] = W3[m * 256 + o * 16 + i];
    } else {
      int r = kk - 512;
      int mp = r >> 4, i = r & 15;
      v[j] = mp ? 0.0f : B3[o * 16 + i];
    }
  }
  uint4 dw;
  dw.x = pk2(v[0], v[1]);
  dw.y = pk2(v[2], v[3]);
  dw.z = pk2(v[4], v[5]);
  dw.w = pk2(v[6], v[7]);
  WF[t] = dw;
}

// ---------------- node init ----------------
__global__ __launch_bounds__(256) void k_node_init(
    const int* __restrict__ species, const float* __restrict__ emb,
    const float* __restrict__ Wq0,
    float* __restrict__ x, float* __restrict__ semb, float* __restrict__ q, int N)
{
  int n = blockIdx.x * 256 + threadIdx.x;
  if (n >= N) return;
  int sp = species[n] - 1;
  float xv[16];
  load16(emb + (size_t)sp * 16, xv);
  store16(x + (size_t)n * 16, xv);
  store16(semb + (size_t)n * 16, xv);
  float qv[8];
#pragma unroll
  for (int h = 0; h < 8; h++) {
    float a = 0.f;
#pragma unroll
    for (int i = 0; i < 16; i++) a += Wq0[h * 16 + i] * xv[i];
    qv[h] = a;
  }
  store8(q + (size_t)n * 8, qv);
}

// ---------------- heavy edge conv ----------------
// Block = 64 edges, 256 threads (4 waves); each wave w MFMAs the 16-edge tile
// [w*16, w*16+16). P layout: [edge][k-dword], stride 148 dwords. h1 computed
// cooperatively (wave w computes m=w*8..w*8+7 for all its lanes' edges,
// shared via h1S[edge][m]). Epilogue stages kv (and ef) through LDS for
// fully-coalesced global writes.
template <int MODE>
__global__ __launch_bounds__(256, 3) void k_edge_conv(
    const int* __restrict__ srcP,
    const float* __restrict__ scaleP, const float* __restrict__ distP,
    float* __restrict__ ef, const float* __restrict__ x,
    const float* __restrict__ W1, const float* __restrict__ B1,
    const float* __restrict__ W2, const float* __restrict__ B2,
    const uint4* __restrict__ WF,
    float* __restrict__ kvT, int E)
{
  __shared__ unsigned P[64 * 148];   // 37888 B; also reused as efS / kvS staging
  __shared__ float h1S[64 * 36];     //  9216 B

  int tid = threadIdx.x;
  int w = __builtin_amdgcn_readfirstlane(tid >> 6);
  int l = tid & 63;
  int quad = l >> 4;
  int lo = l & 15;
  int q4 = quad * 4;
  int eb = blockIdx.x * 64;
  int el = eb + l;

  // ---- xs (redundant across waves; L1/L2 resident) ----
  float xs[16];
  load16(x + (size_t)srcP[el] * 16, xs);

  // ---- ef / h1 (wave w computes m = w*8 .. w*8+7) ----
  float h1v[8];
  if (MODE == 0) {
    float dd = distP[el];
#pragma unroll
    for (int jj = 0; jj < 8; jj++) {
      int m = w * 8 + jj;
      h1v[jj] = fmaxf(B1[m] + dd * W1[15 * 32 + m], 0.f);
    }
  } else {
    float efv[16];
    if (MODE == 1) {
#pragma unroll
      for (int i = 0; i < 16; i++) efv[i] = xs[i];
      efv[15] += distP[el];
    } else {
      const float4* efp = (const float4*)(ef + (size_t)el * 16);
#pragma unroll
      for (int i = 0; i < 4; i++) {
        float4 t = efp[i];
        efv[4*i]   = t.x + xs[4*i];
        efv[4*i+1] = t.y + xs[4*i+1];
        efv[4*i+2] = t.z + xs[4*i+2];
        efv[4*i+3] = t.w + xs[4*i+3];
      }
    }
    if (MODE == 1 || MODE == 2) {
      // stage new ef into LDS (P region) for a coalesced global store
      ((float4*)P)[l * 4 + w] = make_float4(efv[4*w], efv[4*w+1], efv[4*w+2], efv[4*w+3]);
    }
#pragma unroll
    for (int jj = 0; jj < 8; jj++) {
      int m = w * 8 + jj;
      float a = B1[m];
#pragma unroll
      for (int i = 0; i < 16; i++) a += efv[i] * W1[i * 32 + m];
      h1v[jj] = fmaxf(a, 0.f);
    }
  }
  {
    float4* hw = (float4*)&h1S[l * 36 + w * 8];
    hw[0] = make_float4(h1v[0], h1v[1], h1v[2], h1v[3]);
    hw[1] = make_float4(h1v[4], h1v[5], h1v[6], h1v[7]);
  }
  __syncthreads();

  // ---- coalesced ef store ----
  if (MODE == 1 || MODE == 2) {
    float4 v = ((const float4*)P)[tid];
    ((float4*)(ef + (size_t)eb * 16))[tid] = v;
  }

  // ---- h2: full h1 for own edge from LDS; wave computes m-set
  //      {(jj>>2)*16 + w*4 + (jj&3)} ----
  float h1a[32];
  {
    const float4* hp = (const float4*)&h1S[l * 36];
#pragma unroll
    for (int c = 0; c < 8; c++) {
      float4 t = hp[c];
      h1a[4*c] = t.x; h1a[4*c+1] = t.y; h1a[4*c+2] = t.z; h1a[4*c+3] = t.w;
    }
  }
  float h2v[8];
#pragma unroll
  for (int jj = 0; jj < 8; jj++) {
    int m = ((jj >> 2) << 4) + w * 4 + (jj & 3);
    float a = B2[m];
#pragma unroll
    for (int k = 0; k < 32; k++) a += h1a[k] * W2[k * 32 + m];
    h2v[jj] = fmaxf(a, 0.f);
  }
  if (MODE == 1 || MODE == 2) __syncthreads();  // efS fully consumed before P overwrite

  // ---- P half 0 (m = 0..15) + bias rows ----
#pragma unroll
  for (int jj = 0; jj < 4; jj++) {
    int mloc = w * 4 + jj;
    float hm = h2v[jj];
    uint4 d0, d1;
    d0.x = pk2(hm*xs[0],  hm*xs[1]);  d0.y = pk2(hm*xs[2],  hm*xs[3]);
    d0.z = pk2(hm*xs[4],  hm*xs[5]);  d0.w = pk2(hm*xs[6],  hm*xs[7]);
    d1.x = pk2(hm*xs[8],  hm*xs[9]);  d1.y = pk2(hm*xs[10], hm*xs[11]);
    d1.z = pk2(hm*xs[12], hm*xs[13]); d1.w = pk2(hm*xs[14], hm*xs[15]);
    uint4* row = (uint4*)&P[l * 148 + mloc * 8];
    row[0] = d0; row[1] = d1;
  }
  if (w == 0) {
    uint4 d0, d1;
    d0.x = pk2(xs[0],  xs[1]);  d0.y = pk2(xs[2],  xs[3]);
    d0.z = pk2(xs[4],  xs[5]);  d0.w = pk2(xs[6],  xs[7]);
    d1.x = pk2(xs[8],  xs[9]);  d1.y = pk2(xs[10], xs[11]);
    d1.z = pk2(xs[12], xs[13]); d1.w = pk2(xs[14], xs[15]);
    uint4* row = (uint4*)&P[l * 148 + 128];
    row[0] = d0; row[1] = d1;
  }
  if (w == 1) {
    uint4 z = make_uint4(0, 0, 0, 0);
    uint4* row = (uint4*)&P[l * 148 + 136];
    row[0] = z; row[1] = z;
  }
  __syncthreads();

  // ---- MFMA half 0 (frags 0..7) + bias (frag 16) ----
  f32x4 acc = {0.f, 0.f, 0.f, 0.f};
  const unsigned* Arow = &P[(w * 16 + lo) * 148];
#pragma unroll
  for (int t = 0; t < 8; t++) {
    FragU a, b;
    a.u = *(const uint4*)(Arow + t * 16 + q4);
    b.u = WF[t * 64 + l];
    acc = __builtin_amdgcn_mfma_f32_16x16x32_bf16(a.s, b.s, acc, 0, 0, 0);
  }
  {
    FragU a, b;
    a.u = *(const uint4*)(Arow + 128 + q4);
    b.u = WF[16 * 64 + l];
    acc = __builtin_amdgcn_mfma_f32_16x16x32_bf16(a.s, b.s, acc, 0, 0, 0);
  }
  __syncthreads();

  // ---- P half 1 (m = 16..31, same rows) ----
#pragma unroll
  for (int jj = 0; jj < 4; jj++) {
    int mloc = w * 4 + jj;
    float hm = h2v[4 + jj];
    uint4 d0, d1;
    d0.x = pk2(hm*xs[0],  hm*xs[1]);  d0.y = pk2(hm*xs[2],  hm*xs[3]);
    d0.z = pk2(hm*xs[4],  hm*xs[5]);  d0.w = pk2(hm*xs[6],  hm*xs[7]);
    d1.x = pk2(hm*xs[8],  hm*xs[9]);  d1.y = pk2(hm*xs[10], hm*xs[11]);
    d1.z = pk2(hm*xs[12], hm*xs[13]); d1.w = pk2(hm*xs[14], hm*xs[15]);
    uint4* row = (uint4*)&P[l * 148 + mloc * 8];
    row[0] = d0; row[1] = d1;
  }
  __syncthreads();

  // ---- MFMA half 1 (frags 8..15) ----
#pragma unroll
  for (int t = 0; t < 8; t++) {
    FragU a, b;
    a.u = *(const uint4*)(Arow + t * 16 + q4);
    b.u = WF[(8 + t) * 64 + l];
    acc = __builtin_amdgcn_mfma_f32_16x16x32_bf16(a.s, b.s, acc, 0, 0, 0);
  }
  __syncthreads();

  // ---- kv epilogue: stage [o][e] in LDS, then coalesced scaled store ----
  {
    float* kf = (float*)P;
    *(float4*)&kf[lo * 68 + w * 16 + q4] = make_float4(acc[0], acc[1], acc[2], acc[3]);
  }
  __syncthreads();
  {
    int o = tid >> 4;
    int c = tid & 15;
    const float* kf = (const float*)P;
    float4 v = *(const float4*)&kf[o * 68 + c * 4];
    float4 s4 = ((const float4*)(scaleP + eb))[c];
    float4 r = make_float4(v.x * F_Y0 * s4.x, v.y * F_Y0 * s4.y,
                           v.z * F_Y0 * s4.z, v.w * F_Y0 * s4.w);
    ((float4*)(kvT + (size_t)o * E + eb))[c] = r;
  }
}

// ---------------- fused softmax + aggregation gather ----------------
__global__ __launch_bounds__(256) void k_gather_agg(
    const int* __restrict__ row_ptr, const float* __restrict__ scaleP,
    const float* __restrict__ kvT, const float* __restrict__ q,
    float* __restrict__ agg, int N, int E)
{
  int t = blockIdx.x * 256 + threadIdx.x;
  if (t >= N * 8) return;
  int n = t >> 3;
  int h = t & 7;
  float qh = q[t];
  int j0 = row_ptr[n], j1 = row_ptr[n + 1];
  const float* keyrow = kvT + (size_t)(8 + h) * E;
  const float* valrow = kvT + (size_t)h * E;
  float num = 0.f, den = 0.f;
  for (int j = j0; j < j1; ++j) {
    float lg = fminf(keyrow[j] * qh, 60.0f);
    float w = scaleP[j] * expf(lg);
    num += w * valrow[j];
    den += w;
  }
  agg[t] = num / fmaxf(den, 1e-20f);
}

// ---------------- feats gather ----------------
__global__ __launch_bounds__(256) void k_gather_feats(
    const int* __restrict__ row_ptr, const float* __restrict__ kvT,
    float* __restrict__ feats, int N, int E)
{
  int t = blockIdx.x * 256 + threadIdx.x;
  if (t >= N * 16) return;
  int n = t >> 4;
  int o = t & 15;
  int j0 = row_ptr[n], j1 = row_ptr[n + 1];
  const float* row = kvT + (size_t)o * E;
  float a = 0.f;
  for (int j = j0; j < j1; ++j) a += row[j];
  feats[t] = a;
}

// ---------------- node update ----------------
__global__ __launch_bounds__(256) void k_node_update(
    const float* __restrict__ agg, const float* __restrict__ xin,
    const float* __restrict__ Wproj, const float* __restrict__ Wq_next,
    float* __restrict__ xout, float* __restrict__ q, int N)
{
  int n = blockIdx.x * 256 + threadIdx.x;
  if (n >= N) return;
  float cat[24];
  load8(agg + (size_t)n * 8, cat);
  load16(xin + (size_t)n * 16, cat + 8);
  float xn[16];
#pragma unroll
  for (int o = 0; o < 16; o++) {
    float a = 0.f;
#pragma unroll
    for (int j = 0; j < 24; j++) a += Wproj[o * 24 + j] * cat[j];
    xn[o] = a;
  }
  store16(xout + (size_t)n * 16, xn);
  float qv[8];
#pragma unroll
  for (int h = 0; h < 8; h++) {
    float a = 0.f;
#pragma unroll
    for (int i = 0; i < 16; i++) a += Wq_next[h * 16 + i] * xn[i];
    qv[h] = a;
  }
  store8(q + (size_t)n * 8, qv);
}

// ---------------- final node MLP + energy reduction ----------------
__global__ __launch_bounds__(256) void k_node_final(
    const float* __restrict__ x, const float* __restrict__ semb,
    const float* __restrict__ feats, const float* __restrict__ Wself,
    const float* __restrict__ mW1, const float* __restrict__ mb1,
    const float* __restrict__ mW2, const float* __restrict__ mb2,
    const float* __restrict__ mW3, const float* __restrict__ mb3,
    float* __restrict__ out, int N)
{
  int n = blockIdx.x * 256 + threadIdx.x;
  float learned = 0.f;
  if (n < N) {
    float xv[16], ft[16], sb[16];
    load16(x + (size_t)n * 16, xv);
    load16(feats + (size_t)n * 16, ft);
    load16(semb + (size_t)n * 16, sb);
    float cat[32];
#pragma unroll
    for (int i = 0; i < 16; i++) cat[i] = sb[i];
#pragma unroll
    for (int o = 0; o < 16; o++) {
      float a = ft[o];
#pragma unroll
      for (int i = 0; i < 16; i++) a += Wself[o * 16 + i] * xv[i];
      cat[16 + o] = a;
    }
    float hh[16];
#pragma unroll
    for (int j = 0; j < 16; j++) {
      float a = mb1[j];
#pragma unroll
      for (int k = 0; k < 32; k++) a += cat[k] * mW1[k * 16 + j];
      hh[j] = siluf(a);
    }
    float h2[16];
#pragma unroll
    for (int j = 0; j < 16; j++) {
      float a = mb2[j];
#pragma unroll
      for (int k = 0; k < 16; k++) a += hh[k] * mW2[k * 16 + j];
      h2[j] = siluf(a);
    }
    float a = mb3[0];
#pragma unroll
    for (int k = 0; k < 16; k++) a += h2[k] * mW3[k];
    learned = a;
  }
#pragma unroll
  for (int off = 32; off > 0; off >>= 1) learned += __shfl_down(learned, off, 64);
  if ((threadIdx.x & 63) == 0) atomicAdd(out, learned);
}

extern "C" void kernel_launch(void* const* d_in, const int* in_sizes, int n_in,
                              void* d_out, int out_size, void* d_ws, size_t ws_size,
                              hipStream_t stream)
{
  const int*   species = (const int*)d_in[0];
  const int*   src     = (const int*)d_in[1];
  const int*   dst     = (const int*)d_in[2];
  const float* rel_pos = (const float*)d_in[3];
  const float* emb     = (const float*)d_in[4];
  const float* kv_W1   = (const float*)d_in[5];
  const float* kv_b1   = (const float*)d_in[6];
  const float* kv_W2   = (const float*)d_in[7];
  const float* kv_b2   = (const float*)d_in[8];
  const float* kv_W3   = (const float*)d_in[9];
  const float* kv_b3   = (const float*)d_in[10];
  const float* Wq      = (const float*)d_in[11];
  const float* Wproj   = (const float*)d_in[12];
  const float* fin_W1  = (const float*)d_in[13];
  const float* fin_b1  = (const float*)d_in[14];
  const float* fin_W2  = (const float*)d_in[15];
  const float* fin_b2  = (const float*)d_in[16];
  const float* fin_W3  = (const float*)d_in[17];
  const float* fin_b3  = (const float*)d_in[18];
  const float* Wself   = (const float*)d_in[19];
  const float* mlp_W1  = (const float*)d_in[20];
  const float* mlp_b1  = (const float*)d_in[21];
  const float* mlp_W2  = (const float*)d_in[22];
  const float* mlp_b2  = (const float*)d_in[23];
  const float* mlp_W3  = (const float*)d_in[24];
  const float* mlp_b3  = (const float*)d_in[25];

  const int N = in_sizes[0];
  const int E = in_sizes[1];

  char* p = (char*)d_ws;
  auto alloc = [&](size_t bytes) -> void* {
    void* r = (void*)p;
    p += (bytes + 255) & ~(size_t)255;
    return r;
  };
  float* dist_   = (float*)alloc((size_t)E * 4);
  float* scale_  = (float*)alloc((size_t)E * 4);
  float* distP   = (float*)alloc((size_t)E * 4);
  float* scaleP  = (float*)alloc((size_t)E * 4);
  int*   srcP    = (int*)  alloc((size_t)E * 4);
  float* ef      = (float*)alloc((size_t)E * 16 * 4);
  float* kvT     = (float*)alloc((size_t)E * 16 * 4);
  float* xA      = (float*)alloc((size_t)N * 16 * 4);
  float* xB      = (float*)alloc((size_t)N * 16 * 4);
  float* q       = (float*)alloc((size_t)N * 8 * 4);
  float* semb    = (float*)alloc((size_t)N * 16 * 4);
  float* agg     = (float*)alloc((size_t)N * 8 * 4);
  float* feats   = (float*)alloc((size_t)N * 16 * 4);
  int*   cnt     = (int*)  alloc((size_t)N * 4);
  int*   row_ptr = (int*)  alloc((size_t)(N + 1) * 4);
  int*   row_cur = (int*)  alloc((size_t)N * 4);
  int*   bsum    = (int*)  alloc(128 * 4);
  int*   boff    = (int*)  alloc(128 * 4);
  uint4* WF      = (uint4*)alloc((size_t)5 * 17 * 64 * 16);

  dim3 blk(256);
  dim3 egrid((E + 255) / 256);
  dim3 cgrid(E / 64);
  dim3 ngrid((N + 255) / 256);
  dim3 n8grid((N * 8 + 255) / 256);
  dim3 n16grid((N * 16 + 255) / 256);

  hipMemsetAsync(d_out, 0, sizeof(float), stream);
  hipMemsetAsync(cnt, 0, (size_t)N * 4, stream);

  k_prepack<<<dim3(22), blk, 0, stream>>>(kv_W3, kv_b3, fin_W3, fin_b3, WF);

  k_pre<<<egrid, blk, 0, stream>>>(species, src, dst, rel_pos, dist_, scale_,
                                   (float*)d_out, E);
  k_hist<<<egrid, blk, 0, stream>>>(dst, cnt, E);
  k_scan1<<<ngrid, blk, 0, stream>>>(cnt, row_ptr, bsum);
  k_scan2<<<dim3(1), dim3(128), 0, stream>>>(bsum, boff);
  k_scan3<<<ngrid, blk, 0, stream>>>(row_ptr, row_cur, boff, N, E);
  k_scatter<<<egrid, blk, 0, stream>>>(src, dst, dist_, scale_, row_cur,
                                       srcP, distP, scaleP, E);

  k_node_init<<<ngrid, blk, 0, stream>>>(species, emb, Wq, xA, semb, q, N);

  float* xin = xA;
  float* xout = xB;
  for (int l = 0; l < 4; l++) {
    const float* W1 = kv_W1 + (size_t)l * 16 * 32;
    const float* B1 = kv_b1 + (size_t)l * 32;
    const float* W2 = kv_W2 + (size_t)l * 32 * 32;
    const float* B2 = kv_b2 + (size_t)l * 32;
    const uint4* WFl = WF + (size_t)l * 17 * 64;
    const float* Wqn = Wq + (size_t)((l < 3) ? (l + 1) : 0) * 8 * 16;
    if (l == 0) {
      k_edge_conv<0><<<cgrid, blk, 0, stream>>>(srcP, scaleP, distP, ef, xin,
                                                W1, B1, W2, B2, WFl, kvT, E);
    } else if (l == 1) {
      k_edge_conv<1><<<cgrid, blk, 0, stream>>>(srcP, scaleP, distP, ef, xin,
                                                W1, B1, W2, B2, WFl, kvT, E);
    } else {
      k_edge_conv<2><<<cgrid, blk, 0, stream>>>(srcP, scaleP, distP, ef, xin,
                                                W1, B1, W2, B2, WFl, kvT, E);
    }
    k_gather_agg<<<n8grid, blk, 0, stream>>>(row_ptr, scaleP, kvT, q, agg, N, E);
    k_node_update<<<ngrid, blk, 0, stream>>>(agg, xin, Wproj + (size_t)l * 16 * 24, Wqn,
                                             xout, q, N);
    float* tmp = xin; xin = xout; xout = tmp;
  }

  k_edge_conv<3><<<cgrid, blk, 0, stream>>>(srcP, scaleP, distP, ef, xin,
                                            fin_W1, fin_b1, fin_W2, fin_b2,
                                            WF + (size_t)4 * 17 * 64, kvT, E);
  k_gather_feats<<<n16grid, blk, 0, stream>>>(row_ptr, kvT, feats, N, E);
  k_node_final<<<ngrid, blk, 0, stream>>>(xin, semb, feats, Wself,
                                          mlp_W1, mlp_b1, mlp_W2, mlp_b2, mlp_W3, mlp_b3,
                                          (float*)d_out, N);
}

// Round 6
// 804.207 us; speedup vs baseline: 4.9894x; 1.0896x over previous
//
#include <hip/hip_runtime.h>

constexpr float F_Y0     = 0.28209479177387814f;
constexpr float F_CUTOFF = 4.6f;

typedef short short8 __attribute__((ext_vector_type(8)));
typedef float f32x4  __attribute__((ext_vector_type(4)));

__device__ __forceinline__ float siluf(float v) { return v / (1.0f + expf(-v)); }

// gfx950 hardware packed fp32->bf16 (RNE): lo = cvt(a), hi = cvt(b)
__device__ __forceinline__ unsigned pk2(float a, float b) {
  unsigned r;
  asm("v_cvt_pk_bf16_f32 %0, %1, %2" : "=v"(r) : "v"(a), "v"(b));
  return r;
}

union FragU { uint4 u; short8 s; };

__device__ __forceinline__ void load16(const float* p, float* r) {
  const float4* p4 = (const float4*)p;
#pragma unroll
  for (int i = 0; i < 4; i++) {
    float4 t = p4[i];
    r[4*i] = t.x; r[4*i+1] = t.y; r[4*i+2] = t.z; r[4*i+3] = t.w;
  }
}
__device__ __forceinline__ void store16(float* p, const float* r) {
  float4* p4 = (float4*)p;
#pragma unroll
  for (int i = 0; i < 4; i++) p4[i] = make_float4(r[4*i], r[4*i+1], r[4*i+2], r[4*i+3]);
}
__device__ __forceinline__ void load8(const float* p, float* r) {
  const float4* p4 = (const float4*)p;
#pragma unroll
  for (int i = 0; i < 2; i++) {
    float4 t = p4[i];
    r[4*i] = t.x; r[4*i+1] = t.y; r[4*i+2] = t.z; r[4*i+3] = t.w;
  }
}
__device__ __forceinline__ void store8(float* p, const float* r) {
  float4* p4 = (float4*)p;
#pragma unroll
  for (int i = 0; i < 2; i++) p4[i] = make_float4(r[4*i], r[4*i+1], r[4*i+2], r[4*i+3]);
}

// block-level sum of one float per thread -> part[blockIdx.x] (no global atomics)
__device__ __forceinline__ void block_reduce_store(float v, float* part) {
  __shared__ float sred[4];
  int tid = threadIdx.x;
#pragma unroll
  for (int off = 32; off > 0; off >>= 1) v += __shfl_down(v, off, 64);
  if ((tid & 63) == 0) sred[tid >> 6] = v;
  __syncthreads();
  if (tid == 0) part[blockIdx.x] = sred[0] + sred[1] + sred[2] + sred[3];
}

// ---------------- per-edge precompute: dist, scale, Coulomb partial ----------------
__global__ __launch_bounds__(256) void k_pre(
    const int* __restrict__ species, const int* __restrict__ src, const int* __restrict__ dst,
    const float* __restrict__ rel_pos,
    float* __restrict__ dist_, float* __restrict__ scale_,
    float* __restrict__ coul_part, int E)
{
  int e = blockIdx.x * 256 + threadIdx.x;
  float ce = 0.0f;
  if (e < E) {
    float px = rel_pos[3*(size_t)e + 0];
    float py = rel_pos[3*(size_t)e + 1];
    float pz = rel_pos[3*(size_t)e + 2];
    float dist = sqrtf(px*px + py*py + pz*pz);
    float xc = dist * (1.0f / F_CUTOFF);
    bool in_cut = dist < F_CUTOFF;
    float x2 = in_cut ? xc * xc : 0.0f;
    x2 = fminf(x2, 1.0f - 1e-6f);
    float sc = in_cut ? expf(3.0f - 3.0f / (1.0f - x2)) : 0.0f;
    dist_[e] = dist;
    scale_[e] = sc;
    float Zu = (float)species[src[e]];
    float Zv = (float)species[dst[e]];
    float raw = 0.529f * Zu * Zv / (2.0f * dist);
    float au = 0.8854f * 0.529f / (powf(Zu, 0.23f) + powf(Zv, 0.23f));
    float xx = dist / au;
    float screen = 0.1818f   * expf(-3.2f    * xx)
                 + 0.5099f   * expf(-0.9423f * xx)
                 + 0.2802f   * expf(-0.4028f * xx)
                 + 0.02817f  * expf(-0.2016f * xx);
    ce = raw * screen * sc;
  }
  block_reduce_store(ce, coul_part);
}

// ---------------- CSR build ----------------
__global__ __launch_bounds__(256) void k_hist(
    const int* __restrict__ dst, int* __restrict__ cnt, int E)
{
  int e = blockIdx.x * 256 + threadIdx.x;
  if (e < E) atomicAdd(&cnt[dst[e]], 1);
}

__global__ __launch_bounds__(256) void k_scan1(
    const int* __restrict__ cnt, int* __restrict__ row_ptr, int* __restrict__ bsum)
{
  __shared__ int s[256];
  int tid = threadIdx.x;
  int n = blockIdx.x * 256 + tid;
  int v = cnt[n];
  s[tid] = v;
  __syncthreads();
#pragma unroll
  for (int off = 1; off < 256; off <<= 1) {
    int t = (tid >= off) ? s[tid - off] : 0;
    __syncthreads();
    s[tid] += t;
    __syncthreads();
  }
  row_ptr[n] = s[tid] - v;
  if (tid == 255) bsum[blockIdx.x] = s[255];
}

__global__ __launch_bounds__(128) void k_scan2(int* __restrict__ bsum, int* __restrict__ boff)
{
  __shared__ int s[128];
  int tid = threadIdx.x;
  int v = bsum[tid];
  s[tid] = v;
  __syncthreads();
#pragma unroll
  for (int off = 1; off < 128; off <<= 1) {
    int t = (tid >= off) ? s[tid - off] : 0;
    __syncthreads();
    s[tid] += t;
    __syncthreads();
  }
  boff[tid] = s[tid] - v;
}

__global__ __launch_bounds__(256) void k_scan3(
    int* __restrict__ row_ptr, int* __restrict__ row_cur,
    const int* __restrict__ boff, int N, int E)
{
  int n = blockIdx.x * 256 + threadIdx.x;
  int rp = row_ptr[n] + boff[blockIdx.x];
  row_ptr[n] = rp;
  row_cur[n] = rp;
  if (n == 0) row_ptr[N] = E;
}

__global__ __launch_bounds__(256) void k_scatter(
    const int* __restrict__ src, const int* __restrict__ dst,
    const float* __restrict__ dist_, const float* __restrict__ scale_,
    int* __restrict__ row_cur,
    int* __restrict__ srcP, float* __restrict__ distP, float* __restrict__ scaleP, int E)
{
  int e = blockIdx.x * 256 + threadIdx.x;
  if (e >= E) return;
  int d = dst[e];
  int pos = atomicAdd(&row_cur[d], 1);
  srcP[pos] = src[e];
  distP[pos] = dist_[e];
  scaleP[pos] = scale_[e];
}

// ---------------- W3/B3 -> bf16 B-fragment prepack ----------------
__global__ __launch_bounds__(256) void k_prepack(
    const float* __restrict__ kv_W3, const float* __restrict__ kv_b3,
    const float* __restrict__ fin_W3, const float* __restrict__ fin_b3,
    uint4* __restrict__ WF)
{
  int t = blockIdx.x * 256 + threadIdx.x;
  if (t >= 5 * 17 * 64) return;
  int lyr = t / (17 * 64);
  int rem = t - lyr * 17 * 64;
  int f = rem >> 6;
  int l = rem & 63;
  int qq = l >> 4;
  int o = l & 15;
  const float* W3 = (lyr < 4) ? (kv_W3 + (size_t)lyr * 32 * 256) : fin_W3;
  const float* B3 = (lyr < 4) ? (kv_b3 + (size_t)lyr * 256) : fin_b3;
  float v[8];
#pragma unroll
  for (int j = 0; j < 8; j++) {
    int kk = f * 32 + qq * 8 + j;
    if (kk < 512) {
      int m = kk >> 4, i = kk & 15;
      v[j] = W3[m * 256 + o * 16 + i];
    } else {
      int r = kk - 512;
      int mp = r >> 4, i = r & 15;
      v[j] = mp ? 0.0f : B3[o * 16 + i];
    }
  }
  uint4 dw;
  dw.x = pk2(v[0], v[1]);
  dw.y = pk2(v[2], v[3]);
  dw.z = pk2(v[4], v[5]);
  dw.w = pk2(v[6], v[7]);
  WF[t] = dw;
}

// ---------------- node init ----------------
__global__ __launch_bounds__(256) void k_node_init(
    const int* __restrict__ species, const float* __restrict__ emb,
    const float* __restrict__ Wq0,
    float* __restrict__ x, float* __restrict__ semb, float* __restrict__ q, int N)
{
  int n = blockIdx.x * 256 + threadIdx.x;
  if (n >= N) return;
  int sp = species[n] - 1;
  float xv[16];
  load16(emb + (size_t)sp * 16, xv);
  store16(x + (size_t)n * 16, xv);
  store16(semb + (size_t)n * 16, xv);
  float qv[8];
#pragma unroll
  for (int h = 0; h < 8; h++) {
    float a = 0.f;
#pragma unroll
    for (int i = 0; i < 16; i++) a += Wq0[h * 16 + i] * xv[i];
    qv[h] = a;
  }
  store8(q + (size_t)n * 8, qv);
}

// ---------------- heavy edge conv (MFMA) ----------------
template <int MODE>
__global__ __launch_bounds__(256, 3) void k_edge_conv(
    const int* __restrict__ srcP,
    const float* __restrict__ scaleP, const float* __restrict__ distP,
    float* __restrict__ ef, const float* __restrict__ x,
    const float* __restrict__ W1, const float* __restrict__ B1,
    const float* __restrict__ W2, const float* __restrict__ B2,
    const uint4* __restrict__ WF,
    float* __restrict__ kvT, int E)
{
  __shared__ unsigned P[64 * 148];   // 37888 B; also reused as efS / kvS staging
  __shared__ float h1S[64 * 36];     //  9216 B

  int tid = threadIdx.x;
  int w = __builtin_amdgcn_readfirstlane(tid >> 6);
  int l = tid & 63;
  int quad = l >> 4;
  int lo = l & 15;
  int q4 = quad * 4;
  int eb = blockIdx.x * 64;
  int el = eb + l;

  float xs[16];
  load16(x + (size_t)srcP[el] * 16, xs);

  float h1v[8];
  if (MODE == 0) {
    float dd = distP[el];
#pragma unroll
    for (int jj = 0; jj < 8; jj++) {
      int m = w * 8 + jj;
      h1v[jj] = fmaxf(B1[m] + dd * W1[15 * 32 + m], 0.f);
    }
  } else {
    float efv[16];
    if (MODE == 1) {
#pragma unroll
      for (int i = 0; i < 16; i++) efv[i] = xs[i];
      efv[15] += distP[el];
    } else {
      const float4* efp = (const float4*)(ef + (size_t)el * 16);
#pragma unroll
      for (int i = 0; i < 4; i++) {
        float4 t = efp[i];
        efv[4*i]   = t.x + xs[4*i];
        efv[4*i+1] = t.y + xs[4*i+1];
        efv[4*i+2] = t.z + xs[4*i+2];
        efv[4*i+3] = t.w + xs[4*i+3];
      }
    }
    if (MODE == 1 || MODE == 2) {
      ((float4*)P)[l * 4 + w] = make_float4(efv[4*w], efv[4*w+1], efv[4*w+2], efv[4*w+3]);
    }
#pragma unroll
    for (int jj = 0; jj < 8; jj++) {
      int m = w * 8 + jj;
      float a = B1[m];
#pragma unroll
      for (int i = 0; i < 16; i++) a += efv[i] * W1[i * 32 + m];
      h1v[jj] = fmaxf(a, 0.f);
    }
  }
  {
    float4* hw = (float4*)&h1S[l * 36 + w * 8];
    hw[0] = make_float4(h1v[0], h1v[1], h1v[2], h1v[3]);
    hw[1] = make_float4(h1v[4], h1v[5], h1v[6], h1v[7]);
  }
  __syncthreads();

  if (MODE == 1 || MODE == 2) {
    float4 v = ((const float4*)P)[tid];
    ((float4*)(ef + (size_t)eb * 16))[tid] = v;
  }

  float h1a[32];
  {
    const float4* hp = (const float4*)&h1S[l * 36];
#pragma unroll
    for (int c = 0; c < 8; c++) {
      float4 t = hp[c];
      h1a[4*c] = t.x; h1a[4*c+1] = t.y; h1a[4*c+2] = t.z; h1a[4*c+3] = t.w;
    }
  }
  float h2v[8];
#pragma unroll
  for (int jj = 0; jj < 8; jj++) {
    int m = ((jj >> 2) << 4) + w * 4 + (jj & 3);
    float a = B2[m];
#pragma unroll
    for (int k = 0; k < 32; k++) a += h1a[k] * W2[k * 32 + m];
    h2v[jj] = fmaxf(a, 0.f);
  }
  if (MODE == 1 || MODE == 2) __syncthreads();

  // ---- P half 0 (m = 0..15) + bias rows ----
#pragma unroll
  for (int jj = 0; jj < 4; jj++) {
    int mloc = w * 4 + jj;
    float hm = h2v[jj];
    uint4 d0, d1;
    d0.x = pk2(hm*xs[0],  hm*xs[1]);  d0.y = pk2(hm*xs[2],  hm*xs[3]);
    d0.z = pk2(hm*xs[4],  hm*xs[5]);  d0.w = pk2(hm*xs[6],  hm*xs[7]);
    d1.x = pk2(hm*xs[8],  hm*xs[9]);  d1.y = pk2(hm*xs[10], hm*xs[11]);
    d1.z = pk2(hm*xs[12], hm*xs[13]); d1.w = pk2(hm*xs[14], hm*xs[15]);
    uint4* row = (uint4*)&P[l * 148 + mloc * 8];
    row[0] = d0; row[1] = d1;
  }
  if (w == 0) {
    uint4 d0, d1;
    d0.x = pk2(xs[0],  xs[1]);  d0.y = pk2(xs[2],  xs[3]);
    d0.z = pk2(xs[4],  xs[5]);  d0.w = pk2(xs[6],  xs[7]);
    d1.x = pk2(xs[8],  xs[9]);  d1.y = pk2(xs[10], xs[11]);
    d1.z = pk2(xs[12], xs[13]); d1.w = pk2(xs[14], xs[15]);
    uint4* row = (uint4*)&P[l * 148 + 128];
    row[0] = d0; row[1] = d1;
  }
  if (w == 1) {
    uint4 z = make_uint4(0, 0, 0, 0);
    uint4* row = (uint4*)&P[l * 148 + 136];
    row[0] = z; row[1] = z;
  }
  __syncthreads();

  f32x4 acc = {0.f, 0.f, 0.f, 0.f};
  const unsigned* Arow = &P[(w * 16 + lo) * 148];
#pragma unroll
  for (int t = 0; t < 8; t++) {
    FragU a, b;
    a.u = *(const uint4*)(Arow + t * 16 + q4);
    b.u = WF[t * 64 + l];
    acc = __builtin_amdgcn_mfma_f32_16x16x32_bf16(a.s, b.s, acc, 0, 0, 0);
  }
  {
    FragU a, b;
    a.u = *(const uint4*)(Arow + 128 + q4);
    b.u = WF[16 * 64 + l];
    acc = __builtin_amdgcn_mfma_f32_16x16x32_bf16(a.s, b.s, acc, 0, 0, 0);
  }
  __syncthreads();

#pragma unroll
  for (int jj = 0; jj < 4; jj++) {
    int mloc = w * 4 + jj;
    float hm = h2v[4 + jj];
    uint4 d0, d1;
    d0.x = pk2(hm*xs[0],  hm*xs[1]);  d0.y = pk2(hm*xs[2],  hm*xs[3]);
    d0.z = pk2(hm*xs[4],  hm*xs[5]);  d0.w = pk2(hm*xs[6],  hm*xs[7]);
    d1.x = pk2(hm*xs[8],  hm*xs[9]);  d1.y = pk2(hm*xs[10], hm*xs[11]);
    d1.z = pk2(hm*xs[12], hm*xs[13]); d1.w = pk2(hm*xs[14], hm*xs[15]);
    uint4* row = (uint4*)&P[l * 148 + mloc * 8];
    row[0] = d0; row[1] = d1;
  }
  __syncthreads();

#pragma unroll
  for (int t = 0; t < 8; t++) {
    FragU a, b;
    a.u = *(const uint4*)(Arow + t * 16 + q4);
    b.u = WF[(8 + t) * 64 + l];
    acc = __builtin_amdgcn_mfma_f32_16x16x32_bf16(a.s, b.s, acc, 0, 0, 0);
  }
  __syncthreads();

  {
    float* kf = (float*)P;
    *(float4*)&kf[lo * 68 + w * 16 + q4] = make_float4(acc[0], acc[1], acc[2], acc[3]);
  }
  __syncthreads();
  {
    int o = tid >> 4;
    int c = tid & 15;
    const float* kf = (const float*)P;
    float4 v = *(const float4*)&kf[o * 68 + c * 4];
    float4 s4 = ((const float4*)(scaleP + eb))[c];
    float4 r = make_float4(v.x * F_Y0 * s4.x, v.y * F_Y0 * s4.y,
                           v.z * F_Y0 * s4.z, v.w * F_Y0 * s4.w);
    ((float4*)(kvT + (size_t)o * E + eb))[c] = r;
  }
}

// ---------------- fused softmax + aggregation gather ----------------
__global__ __launch_bounds__(256) void k_gather_agg(
    const int* __restrict__ row_ptr, const float* __restrict__ scaleP,
    const float* __restrict__ kvT, const float* __restrict__ q,
    float* __restrict__ agg, int N, int E)
{
  int t = blockIdx.x * 256 + threadIdx.x;
  if (t >= N * 8) return;
  int n = t >> 3;
  int h = t & 7;
  float qh = q[t];
  int j0 = row_ptr[n], j1 = row_ptr[n + 1];
  const float* keyrow = kvT + (size_t)(8 + h) * E;
  const float* valrow = kvT + (size_t)h * E;
  float num = 0.f, den = 0.f;
  for (int j = j0; j < j1; ++j) {
    float lg = fminf(keyrow[j] * qh, 60.0f);
    float w = scaleP[j] * expf(lg);
    num += w * valrow[j];
    den += w;
  }
  agg[t] = num / fmaxf(den, 1e-20f);
}

// ---------------- feats gather ----------------
__global__ __launch_bounds__(256) void k_gather_feats(
    const int* __restrict__ row_ptr, const float* __restrict__ kvT,
    float* __restrict__ feats, int N, int E)
{
  int t = blockIdx.x * 256 + threadIdx.x;
  if (t >= N * 16) return;
  int n = t >> 4;
  int o = t & 15;
  int j0 = row_ptr[n], j1 = row_ptr[n + 1];
  const float* row = kvT + (size_t)o * E;
  float a = 0.f;
  for (int j = j0; j < j1; ++j) a += row[j];
  feats[t] = a;
}

// ---------------- node update ----------------
__global__ __launch_bounds__(256) void k_node_update(
    const float* __restrict__ agg, const float* __restrict__ xin,
    const float* __restrict__ Wproj, const float* __restrict__ Wq_next,
    float* __restrict__ xout, float* __restrict__ q, int N)
{
  int n = blockIdx.x * 256 + threadIdx.x;
  if (n >= N) return;
  float cat[24];
  load8(agg + (size_t)n * 8, cat);
  load16(xin + (size_t)n * 16, cat + 8);
  float xn[16];
#pragma unroll
  for (int o = 0; o < 16; o++) {
    float a = 0.f;
#pragma unroll
    for (int j = 0; j < 24; j++) a += Wproj[o * 24 + j] * cat[j];
    xn[o] = a;
  }
  store16(xout + (size_t)n * 16, xn);
  float qv[8];
#pragma unroll
  for (int h = 0; h < 8; h++) {
    float a = 0.f;
#pragma unroll
    for (int i = 0; i < 16; i++) a += Wq_next[h * 16 + i] * xn[i];
    qv[h] = a;
  }
  store8(q + (size_t)n * 8, qv);
}

// ---------------- final node MLP -> per-block partials ----------------
__global__ __launch_bounds__(256) void k_node_final(
    const float* __restrict__ x, const float* __restrict__ semb,
    const float* __restrict__ feats, const float* __restrict__ Wself,
    const float* __restrict__ mW1, const float* __restrict__ mb1,
    const float* __restrict__ mW2, const float* __restrict__ mb2,
    const float* __restrict__ mW3, const float* __restrict__ mb3,
    float* __restrict__ learn_part, int N)
{
  int n = blockIdx.x * 256 + threadIdx.x;
  float learned = 0.f;
  if (n < N) {
    float xv[16], ft[16], sb[16];
    load16(x + (size_t)n * 16, xv);
    load16(feats + (size_t)n * 16, ft);
    load16(semb + (size_t)n * 16, sb);
    float cat[32];
#pragma unroll
    for (int i = 0; i < 16; i++) cat[i] = sb[i];
#pragma unroll
    for (int o = 0; o < 16; o++) {
      float a = ft[o];
#pragma unroll
      for (int i = 0; i < 16; i++) a += Wself[o * 16 + i] * xv[i];
      cat[16 + o] = a;
    }
    float hh[16];
#pragma unroll
    for (int j = 0; j < 16; j++) {
      float a = mb1[j];
#pragma unroll
      for (int k = 0; k < 32; k++) a += cat[k] * mW1[k * 16 + j];
      hh[j] = siluf(a);
    }
    float h2[16];
#pragma unroll
    for (int j = 0; j < 16; j++) {
      float a = mb2[j];
#pragma unroll
      for (int k = 0; k < 16; k++) a += hh[k] * mW2[k * 16 + j];
      h2[j] = siluf(a);
    }
    float a = mb3[0];
#pragma unroll
    for (int k = 0; k < 16; k++) a += h2[k] * mW3[k];
    learned = a;
  }
  block_reduce_store(learned, learn_part);
}

// ---------------- final reduction: sum partials -> d_out ----------------
__global__ __launch_bounds__(256) void k_finalize(
    const float* __restrict__ coul_part, int nc,
    const float* __restrict__ learn_part, int nl,
    float* __restrict__ out)
{
  __shared__ float sred[4];
  int tid = threadIdx.x;
  float v = 0.f;
  for (int i = tid; i < nc; i += 256) v += coul_part[i];
  for (int i = tid; i < nl; i += 256) v += learn_part[i];
#pragma unroll
  for (int off = 32; off > 0; off >>= 1) v += __shfl_down(v, off, 64);
  if ((tid & 63) == 0) sred[tid >> 6] = v;
  __syncthreads();
  if (tid == 0) out[0] = sred[0] + sred[1] + sred[2] + sred[3];
}

extern "C" void kernel_launch(void* const* d_in, const int* in_sizes, int n_in,
                              void* d_out, int out_size, void* d_ws, size_t ws_size,
                              hipStream_t stream)
{
  const int*   species = (const int*)d_in[0];
  const int*   src     = (const int*)d_in[1];
  const int*   dst     = (const int*)d_in[2];
  const float* rel_pos = (const float*)d_in[3];
  const float* emb     = (const float*)d_in[4];
  const float* kv_W1   = (const float*)d_in[5];
  const float* kv_b1   = (const float*)d_in[6];
  const float* kv_W2   = (const float*)d_in[7];
  const float* kv_b2   = (const float*)d_in[8];
  const float* kv_W3   = (const float*)d_in[9];
  const float* kv_b3   = (const float*)d_in[10];
  const float* Wq      = (const float*)d_in[11];
  const float* Wproj   = (const float*)d_in[12];
  const float* fin_W1  = (const float*)d_in[13];
  const float* fin_b1  = (const float*)d_in[14];
  const float* fin_W2  = (const float*)d_in[15];
  const float* fin_b2  = (const float*)d_in[16];
  const float* fin_W3  = (const float*)d_in[17];
  const float* fin_b3  = (const float*)d_in[18];
  const float* Wself   = (const float*)d_in[19];
  const float* mlp_W1  = (const float*)d_in[20];
  const float* mlp_b1  = (const float*)d_in[21];
  const float* mlp_W2  = (const float*)d_in[22];
  const float* mlp_b2  = (const float*)d_in[23];
  const float* mlp_W3  = (const float*)d_in[24];
  const float* mlp_b3  = (const float*)d_in[25];

  const int N = in_sizes[0];
  const int E = in_sizes[1];
  const int nblk_e = (E + 255) / 256;
  const int nblk_n = (N + 255) / 256;

  char* p = (char*)d_ws;
  auto alloc = [&](size_t bytes) -> void* {
    void* r = (void*)p;
    p += (bytes + 255) & ~(size_t)255;
    return r;
  };
  float* dist_   = (float*)alloc((size_t)E * 4);
  float* scale_  = (float*)alloc((size_t)E * 4);
  float* distP   = (float*)alloc((size_t)E * 4);
  float* scaleP  = (float*)alloc((size_t)E * 4);
  int*   srcP    = (int*)  alloc((size_t)E * 4);
  float* ef      = (float*)alloc((size_t)E * 16 * 4);
  float* kvT     = (float*)alloc((size_t)E * 16 * 4);
  float* xA      = (float*)alloc((size_t)N * 16 * 4);
  float* xB      = (float*)alloc((size_t)N * 16 * 4);
  float* q       = (float*)alloc((size_t)N * 8 * 4);
  float* semb    = (float*)alloc((size_t)N * 16 * 4);
  float* agg     = (float*)alloc((size_t)N * 8 * 4);
  float* feats   = (float*)alloc((size_t)N * 16 * 4);
  int*   cnt     = (int*)  alloc((size_t)N * 4);
  int*   row_ptr = (int*)  alloc((size_t)(N + 1) * 4);
  int*   row_cur = (int*)  alloc((size_t)N * 4);
  int*   bsum    = (int*)  alloc(128 * 4);
  int*   boff    = (int*)  alloc(128 * 4);
  uint4* WF      = (uint4*)alloc((size_t)5 * 17 * 64 * 16);
  float* coul_part  = (float*)alloc((size_t)nblk_e * 4);
  float* learn_part = (float*)alloc((size_t)nblk_n * 4);

  dim3 blk(256);
  dim3 egrid(nblk_e);
  dim3 cgrid(E / 64);
  dim3 ngrid(nblk_n);
  dim3 n8grid((N * 8 + 255) / 256);
  dim3 n16grid((N * 16 + 255) / 256);

  hipMemsetAsync(cnt, 0, (size_t)N * 4, stream);

  k_prepack<<<dim3(22), blk, 0, stream>>>(kv_W3, kv_b3, fin_W3, fin_b3, WF);

  k_pre<<<egrid, blk, 0, stream>>>(species, src, dst, rel_pos, dist_, scale_,
                                   coul_part, E);
  k_hist<<<egrid, blk, 0, stream>>>(dst, cnt, E);
  k_scan1<<<ngrid, blk, 0, stream>>>(cnt, row_ptr, bsum);
  k_scan2<<<dim3(1), dim3(128), 0, stream>>>(bsum, boff);
  k_scan3<<<ngrid, blk, 0, stream>>>(row_ptr, row_cur, boff, N, E);
  k_scatter<<<egrid, blk, 0, stream>>>(src, dst, dist_, scale_, row_cur,
                                       srcP, distP, scaleP, E);

  k_node_init<<<ngrid, blk, 0, stream>>>(species, emb, Wq, xA, semb, q, N);

  float* xin = xA;
  float* xout = xB;
  for (int l = 0; l < 4; l++) {
    const float* W1 = kv_W1 + (size_t)l * 16 * 32;
    const float* B1 = kv_b1 + (size_t)l * 32;
    const float* W2 = kv_W2 + (size_t)l * 32 * 32;
    const float* B2 = kv_b2 + (size_t)l * 32;
    const uint4* WFl = WF + (size_t)l * 17 * 64;
    const float* Wqn = Wq + (size_t)((l < 3) ? (l + 1) : 0) * 8 * 16;
    if (l == 0) {
      k_edge_conv<0><<<cgrid, blk, 0, stream>>>(srcP, scaleP, distP, ef, xin,
                                                W1, B1, W2, B2, WFl, kvT, E);
    } else if (l == 1) {
      k_edge_conv<1><<<cgrid, blk, 0, stream>>>(srcP, scaleP, distP, ef, xin,
                                                W1, B1, W2, B2, WFl, kvT, E);
    } else {
      k_edge_conv<2><<<cgrid, blk, 0, stream>>>(srcP, scaleP, distP, ef, xin,
                                                W1, B1, W2, B2, WFl, kvT, E);
    }
    k_gather_agg<<<n8grid, blk, 0, stream>>>(row_ptr, scaleP, kvT, q, agg, N, E);
    k_node_update<<<ngrid, blk, 0, stream>>>(agg, xin, Wproj + (size_t)l * 16 * 24, Wqn,
                                             xout, q, N);
    float* tmp = xin; xin = xout; xout = tmp;
  }

  k_edge_conv<3><<<cgrid, blk, 0, stream>>>(srcP, scaleP, distP, ef, xin,
                                            fin_W1, fin_b1, fin_W2, fin_b2,
                                            WF + (size_t)4 * 17 * 64, kvT, E);
  k_gather_feats<<<n16grid, blk, 0, stream>>>(row_ptr, kvT, feats, N, E);
  k_node_final<<<ngrid, blk, 0, stream>>>(xin, semb, feats, Wself,
                                          mlp_W1, mlp_b1, mlp_W2, mlp_b2, mlp_W3, mlp_b3,
                                          learn_part, N);
  k_finalize<<<dim3(1), blk, 0, stream>>>(coul_part, nblk_e, learn_part, nblk_n,
                                          (float*)d_out);
}

// Round 7
// 640.347 us; speedup vs baseline: 6.2662x; 1.2559x over previous
//
#include <hip/hip_runtime.h>

constexpr float F_Y0     = 0.28209479177387814f;
constexpr float F_CUTOFF = 4.6f;

typedef short short8 __attribute__((ext_vector_type(8)));
typedef float f32x4  __attribute__((ext_vector_type(4)));

__device__ __forceinline__ float siluf(float v) { return v / (1.0f + expf(-v)); }

// gfx950 hardware packed fp32->bf16 (RNE): lo = cvt(a), hi = cvt(b)
__device__ __forceinline__ unsigned pk2(float a, float b) {
  unsigned r;
  asm("v_cvt_pk_bf16_f32 %0, %1, %2" : "=v"(r) : "v"(a), "v"(b));
  return r;
}

union FragU { uint4 u; short8 s; };

__device__ __forceinline__ void load16(const float* p, float* r) {
  const float4* p4 = (const float4*)p;
#pragma unroll
  for (int i = 0; i < 4; i++) {
    float4 t = p4[i];
    r[4*i] = t.x; r[4*i+1] = t.y; r[4*i+2] = t.z; r[4*i+3] = t.w;
  }
}
__device__ __forceinline__ void store16(float* p, const float* r) {
  float4* p4 = (float4*)p;
#pragma unroll
  for (int i = 0; i < 4; i++) p4[i] = make_float4(r[4*i], r[4*i+1], r[4*i+2], r[4*i+3]);
}
__device__ __forceinline__ void load8(const float* p, float* r) {
  const float4* p4 = (const float4*)p;
#pragma unroll
  for (int i = 0; i < 2; i++) {
    float4 t = p4[i];
    r[4*i] = t.x; r[4*i+1] = t.y; r[4*i+2] = t.z; r[4*i+3] = t.w;
  }
}
__device__ __forceinline__ void store8(float* p, const float* r) {
  float4* p4 = (float4*)p;
#pragma unroll
  for (int i = 0; i < 2; i++) p4[i] = make_float4(r[4*i], r[4*i+1], r[4*i+2], r[4*i+3]);
}

// block-level sum of one float per thread -> part[blockIdx.x]
__device__ __forceinline__ void block_reduce_store(float v, float* part) {
  __shared__ float sred[4];
  int tid = threadIdx.x;
#pragma unroll
  for (int off = 32; off > 0; off >>= 1) v += __shfl_down(v, off, 64);
  if ((tid & 63) == 0) sred[tid >> 6] = v;
  __syncthreads();
  if (tid == 0) part[blockIdx.x] = sred[0] + sred[1] + sred[2] + sred[3];
}

// ---------------- per-edge precompute ----------------
__global__ __launch_bounds__(256) void k_pre(
    const int* __restrict__ species, const int* __restrict__ src, const int* __restrict__ dst,
    const float* __restrict__ rel_pos,
    float* __restrict__ dist_, float* __restrict__ scale_,
    float* __restrict__ coul_part, int E)
{
  int e = blockIdx.x * 256 + threadIdx.x;
  float ce = 0.0f;
  if (e < E) {
    float px = rel_pos[3*(size_t)e + 0];
    float py = rel_pos[3*(size_t)e + 1];
    float pz = rel_pos[3*(size_t)e + 2];
    float dist = sqrtf(px*px + py*py + pz*pz);
    float xc = dist * (1.0f / F_CUTOFF);
    bool in_cut = dist < F_CUTOFF;
    float x2 = in_cut ? xc * xc : 0.0f;
    x2 = fminf(x2, 1.0f - 1e-6f);
    float sc = in_cut ? __expf(3.0f - 3.0f / (1.0f - x2)) : 0.0f;
    dist_[e] = dist;
    scale_[e] = sc;
    float Zu = (float)species[src[e]];
    float Zv = (float)species[dst[e]];
    float raw = 0.529f * Zu * Zv / (2.0f * dist);
    float au = 0.8854f * 0.529f / (__powf(Zu, 0.23f) + __powf(Zv, 0.23f));
    float xx = dist / au;
    float screen = 0.1818f   * __expf(-3.2f    * xx)
                 + 0.5099f   * __expf(-0.9423f * xx)
                 + 0.2802f   * __expf(-0.4028f * xx)
                 + 0.02817f  * __expf(-0.2016f * xx);
    ce = raw * screen * sc;
  }
  block_reduce_store(ce, coul_part);
}

// ---------------- CSR build ----------------
__global__ __launch_bounds__(256) void k_hist(
    const int* __restrict__ dst, int* __restrict__ cnt, int E)
{
  int e = blockIdx.x * 256 + threadIdx.x;
  if (e < E) atomicAdd(&cnt[dst[e]], 1);
}

__global__ __launch_bounds__(256) void k_scan1(
    const int* __restrict__ cnt, int* __restrict__ row_ptr, int* __restrict__ bsum)
{
  __shared__ int s[256];
  int tid = threadIdx.x;
  int n = blockIdx.x * 256 + tid;
  int v = cnt[n];
  s[tid] = v;
  __syncthreads();
#pragma unroll
  for (int off = 1; off < 256; off <<= 1) {
    int t = (tid >= off) ? s[tid - off] : 0;
    __syncthreads();
    s[tid] += t;
    __syncthreads();
  }
  row_ptr[n] = s[tid] - v;
  if (tid == 255) bsum[blockIdx.x] = s[255];
}

__global__ __launch_bounds__(128) void k_scan2(int* __restrict__ bsum, int* __restrict__ boff)
{
  __shared__ int s[128];
  int tid = threadIdx.x;
  int v = bsum[tid];
  s[tid] = v;
  __syncthreads();
#pragma unroll
  for (int off = 1; off < 128; off <<= 1) {
    int t = (tid >= off) ? s[tid - off] : 0;
    __syncthreads();
    s[tid] += t;
    __syncthreads();
  }
  boff[tid] = s[tid] - v;
}

__global__ __launch_bounds__(256) void k_scan3(
    int* __restrict__ row_ptr, int* __restrict__ row_cur,
    const int* __restrict__ boff, int N, int E)
{
  int n = blockIdx.x * 256 + threadIdx.x;
  int rp = row_ptr[n] + boff[blockIdx.x];
  row_ptr[n] = rp;
  row_cur[n] = rp;
  if (n == 0) row_ptr[N] = E;
}

__global__ __launch_bounds__(256) void k_scatter(
    const int* __restrict__ src, const int* __restrict__ dst,
    const float* __restrict__ dist_, const float* __restrict__ scale_,
    int* __restrict__ row_cur,
    int* __restrict__ srcP, float* __restrict__ distP, float* __restrict__ scaleP, int E)
{
  int e = blockIdx.x * 256 + threadIdx.x;
  if (e >= E) return;
  int d = dst[e];
  int pos = atomicAdd(&row_cur[d], 1);
  srcP[pos] = src[e];
  distP[pos] = dist_[e];
  scaleP[pos] = scale_[e];
}

// ---------------- weight prepack: per layer 19 bf16 B-fragments ----------------
// frags 0..15: W3 (linear K: kk=m*16+i), frag 16: bias block (B3 row + zeros),
// frags 17..18: W2 (n-tile 0/1, k = h1 index 0..31).
__global__ __launch_bounds__(256) void k_prepack(
    const float* __restrict__ kv_W3, const float* __restrict__ kv_b3,
    const float* __restrict__ fin_W3, const float* __restrict__ fin_b3,
    const float* __restrict__ kv_W2, const float* __restrict__ fin_W2,
    uint4* __restrict__ WF)
{
  int t = blockIdx.x * 256 + threadIdx.x;
  if (t >= 5 * 19 * 64) return;
  int lyr = t / (19 * 64);
  int rem = t - lyr * 19 * 64;
  int f = rem >> 6;
  int l = rem & 63;
  int qq = l >> 4;
  int o = l & 15;
  const float* W3 = (lyr < 4) ? (kv_W3 + (size_t)lyr * 32 * 256) : fin_W3;
  const float* B3 = (lyr < 4) ? (kv_b3 + (size_t)lyr * 256) : fin_b3;
  const float* W2 = (lyr < 4) ? (kv_W2 + (size_t)lyr * 32 * 32) : fin_W2;
  float v[8];
#pragma unroll
  for (int j = 0; j < 8; j++) {
    if (f < 16) {
      int kk = f * 32 + qq * 8 + j;
      int m = kk >> 4, i = kk & 15;
      v[j] = W3[m * 256 + o * 16 + i];
    } else if (f == 16) {
      int r = qq * 8 + j;
      int mp = r >> 4, i = r & 15;
      v[j] = mp ? 0.0f : B3[o * 16 + i];
    } else {
      int c = f - 17;
      int k = qq * 8 + j;
      v[j] = W2[k * 32 + c * 16 + o];
    }
  }
  uint4 dw;
  dw.x = pk2(v[0], v[1]);
  dw.y = pk2(v[2], v[3]);
  dw.z = pk2(v[4], v[5]);
  dw.w = pk2(v[6], v[7]);
  WF[t] = dw;
}

// ---------------- node init ----------------
__global__ __launch_bounds__(256) void k_node_init(
    const int* __restrict__ species, const float* __restrict__ emb,
    const float* __restrict__ Wq0,
    float* __restrict__ x, float* __restrict__ semb, float* __restrict__ q, int N)
{
  int n = blockIdx.x * 256 + threadIdx.x;
  if (n >= N) return;
  int sp = species[n] - 1;
  float xv[16];
  load16(emb + (size_t)sp * 16, xv);
  store16(x + (size_t)n * 16, xv);
  store16(semb + (size_t)n * 16, xv);
  float qv[8];
#pragma unroll
  for (int h = 0; h < 8; h++) {
    float a = 0.f;
#pragma unroll
    for (int i = 0; i < 16; i++) a += Wq0[h * 16 + i] * xv[i];
    qv[h] = a;
  }
  store8(q + (size_t)n * 8, qv);
}

// ---------------- heavy edge conv (MFMA for h2 and W3) ----------------
// Block = 64 edges, 4 waves; wave w owns the 16-edge MFMA tile [w*16, w*16+16).
// h1: wave w computes m=w*8..w*8+7 per lane-edge (VALU), packed bf16 into h1P.
// h2 = relu(h1 @ W2 + B2) via 2 MFMA; routed per-edge through h2S (fp32).
// kv = (P @ W3F) with P = h2 (x) xs built in two halves; D stored directly
// to kvE[e][16] from C-regs (C rows are edges -> coalesced lines).
template <int MODE>
__global__ __launch_bounds__(256, 3) void k_edge_conv(
    const int* __restrict__ srcP,
    const float* __restrict__ scaleP, const float* __restrict__ distP,
    float* __restrict__ ef, const float* __restrict__ x,
    const float* __restrict__ W1, const float* __restrict__ B1,
    const float* __restrict__ B2,
    const uint4* __restrict__ WF,
    float* __restrict__ kvE, int E)
{
  __shared__ unsigned P[64 * 148];    // 37888 B; start reused as ef staging (stride 20)
  __shared__ unsigned h1P[64 * 20];   //  5120 B  bf16 h1 [edge][16 dw + pad]
  __shared__ float    h2S[64 * 36];   //  9216 B  fp32 h2 [edge][32 + pad]

  int tid = threadIdx.x;
  int w = __builtin_amdgcn_readfirstlane(tid >> 6);
  int l = tid & 63;
  int quad = l >> 4;
  int lo = l & 15;
  int q4 = quad * 4;
  int eb = blockIdx.x * 64;
  int el = eb + l;

  float xs[16];
  load16(x + (size_t)srcP[el] * 16, xs);

  // ---- h1 (wave w: m = w*8 .. w*8+7) ----
  float h1v[8];
  if (MODE == 0) {
    float dd = distP[el];
#pragma unroll
    for (int jj = 0; jj < 8; jj++) {
      int m = w * 8 + jj;
      h1v[jj] = fmaxf(B1[m] + dd * W1[15 * 32 + m], 0.f);
    }
  } else {
    float efv[16];
    if (MODE == 1) {
#pragma unroll
      for (int i = 0; i < 16; i++) efv[i] = xs[i];
      efv[15] += distP[el];
    } else {
      const float4* efp = (const float4*)(ef + (size_t)el * 16);
#pragma unroll
      for (int i = 0; i < 4; i++) {
        float4 t = efp[i];
        efv[4*i]   = t.x + xs[4*i];
        efv[4*i+1] = t.y + xs[4*i+1];
        efv[4*i+2] = t.z + xs[4*i+2];
        efv[4*i+3] = t.w + xs[4*i+3];
      }
    }
    if (MODE == 1 || MODE == 2) {
      // stage new ef (stride 20 dwords: conflict-free b128 writes)
      *(float4*)&((float*)P)[l * 20 + w * 4] =
          make_float4(efv[4*w], efv[4*w+1], efv[4*w+2], efv[4*w+3]);
    }
#pragma unroll
    for (int jj = 0; jj < 8; jj++) {
      int m = w * 8 + jj;
      float a = B1[m];
#pragma unroll
      for (int i = 0; i < 16; i++) a += efv[i] * W1[i * 32 + m];
      h1v[jj] = fmaxf(a, 0.f);
    }
  }
  {
    uint4 hq;
    hq.x = pk2(h1v[0], h1v[1]);
    hq.y = pk2(h1v[2], h1v[3]);
    hq.z = pk2(h1v[4], h1v[5]);
    hq.w = pk2(h1v[6], h1v[7]);
    *(uint4*)&h1P[l * 20 + w * 4] = hq;
  }
  __syncthreads();   // S1: efS + h1P ready

  if (MODE == 1 || MODE == 2) {
    int e = tid >> 2, c = tid & 3;
    float4 v = *(const float4*)&((const float*)P)[e * 20 + c * 4];
    ((float4*)(ef + (size_t)eb * 16))[tid] = v;
  }

  // ---- h2 via MFMA: A = bf16 h1 tile, B = W2 frags (17,18) ----
  {
    FragU a, b0, b1;
    a.u = *(const uint4*)&h1P[(w * 16 + lo) * 20 + q4];
    b0.u = WF[17 * 64 + l];
    b1.u = WF[18 * 64 + l];
    f32x4 hc0 = {0.f, 0.f, 0.f, 0.f};
    f32x4 hc1 = {0.f, 0.f, 0.f, 0.f};
    hc0 = __builtin_amdgcn_mfma_f32_16x16x32_bf16(a.s, b0.s, hc0, 0, 0, 0);
    hc1 = __builtin_amdgcn_mfma_f32_16x16x32_bf16(a.s, b1.s, hc1, 0, 0, 0);
    float b2a = B2[lo];
    float b2b = B2[16 + lo];
#pragma unroll
    for (int r = 0; r < 4; r++) {
      int e = quad * 4 + r;
      h2S[(w * 16 + e) * 36 + lo]      = fmaxf(hc0[r] + b2a, 0.f);
      h2S[(w * 16 + e) * 36 + 16 + lo] = fmaxf(hc1[r] + b2b, 0.f);
    }
  }
  __syncthreads();   // S2: h2S ready; efS consumed

  // ---- own-edge h2 (fp32) ----
  float h2a[32];
  {
    const float4* hp = (const float4*)&h2S[l * 36];
#pragma unroll
    for (int c = 0; c < 8; c++) {
      float4 t = hp[c];
      h2a[4*c] = t.x; h2a[4*c+1] = t.y; h2a[4*c+2] = t.z; h2a[4*c+3] = t.w;
    }
  }

  // ---- P half 0 (m = 0..15) + bias rows ----
#pragma unroll
  for (int jj = 0; jj < 4; jj++) {
    int mloc = w * 4 + jj;
    float hm = h2a[mloc];
    uint4 d0, d1;
    d0.x = pk2(hm*xs[0],  hm*xs[1]);  d0.y = pk2(hm*xs[2],  hm*xs[3]);
    d0.z = pk2(hm*xs[4],  hm*xs[5]);  d0.w = pk2(hm*xs[6],  hm*xs[7]);
    d1.x = pk2(hm*xs[8],  hm*xs[9]);  d1.y = pk2(hm*xs[10], hm*xs[11]);
    d1.z = pk2(hm*xs[12], hm*xs[13]); d1.w = pk2(hm*xs[14], hm*xs[15]);
    uint4* row = (uint4*)&P[l * 148 + mloc * 8];
    row[0] = d0; row[1] = d1;
  }
  if (w == 0) {
    uint4 d0, d1;
    d0.x = pk2(xs[0],  xs[1]);  d0.y = pk2(xs[2],  xs[3]);
    d0.z = pk2(xs[4],  xs[5]);  d0.w = pk2(xs[6],  xs[7]);
    d1.x = pk2(xs[8],  xs[9]);  d1.y = pk2(xs[10], xs[11]);
    d1.z = pk2(xs[12], xs[13]); d1.w = pk2(xs[14], xs[15]);
    uint4* row = (uint4*)&P[l * 148 + 128];
    row[0] = d0; row[1] = d1;
  }
  if (w == 1) {
    uint4 z = make_uint4(0, 0, 0, 0);
    uint4* row = (uint4*)&P[l * 148 + 136];
    row[0] = z; row[1] = z;
  }
  __syncthreads();   // S3

  f32x4 acc = {0.f, 0.f, 0.f, 0.f};
  const unsigned* Arow = &P[(w * 16 + lo) * 148];
#pragma unroll
  for (int t = 0; t < 8; t++) {
    FragU a, b;
    a.u = *(const uint4*)(Arow + t * 16 + q4);
    b.u = WF[t * 64 + l];
    acc = __builtin_amdgcn_mfma_f32_16x16x32_bf16(a.s, b.s, acc, 0, 0, 0);
  }
  {
    FragU a, b;
    a.u = *(const uint4*)(Arow + 128 + q4);
    b.u = WF[16 * 64 + l];
    acc = __builtin_amdgcn_mfma_f32_16x16x32_bf16(a.s, b.s, acc, 0, 0, 0);
  }
  __syncthreads();   // S4

  // ---- P half 1 (m = 16..31) ----
#pragma unroll
  for (int jj = 0; jj < 4; jj++) {
    int mloc = w * 4 + jj;
    float hm = h2a[16 + mloc];
    uint4 d0, d1;
    d0.x = pk2(hm*xs[0],  hm*xs[1]);  d0.y = pk2(hm*xs[2],  hm*xs[3]);
    d0.z = pk2(hm*xs[4],  hm*xs[5]);  d0.w = pk2(hm*xs[6],  hm*xs[7]);
    d1.x = pk2(hm*xs[8],  hm*xs[9]);  d1.y = pk2(hm*xs[10], hm*xs[11]);
    d1.z = pk2(hm*xs[12], hm*xs[13]); d1.w = pk2(hm*xs[14], hm*xs[15]);
    uint4* row = (uint4*)&P[l * 148 + mloc * 8];
    row[0] = d0; row[1] = d1;
  }
  __syncthreads();   // S5

#pragma unroll
  for (int t = 0; t < 8; t++) {
    FragU a, b;
    a.u = *(const uint4*)(Arow + t * 16 + q4);
    b.u = WF[(8 + t) * 64 + l];
    acc = __builtin_amdgcn_mfma_f32_16x16x32_bf16(a.s, b.s, acc, 0, 0, 0);
  }

  // ---- direct epilogue: kvE[e][o] from C-regs (rows = edges) ----
#pragma unroll
  for (int r = 0; r < 4; r++) {
    int ee = eb + w * 16 + quad * 4 + r;
    float bsc = F_Y0 * scaleP[ee];
    kvE[(size_t)ee * 16 + lo] = acc[r] * bsc;
  }
}

// ---------------- fused softmax + aggregation gather (kvE layout) ----------------
__global__ __launch_bounds__(256) void k_gather_agg(
    const int* __restrict__ row_ptr, const float* __restrict__ scaleP,
    const float* __restrict__ kvE, const float* __restrict__ q,
    float* __restrict__ agg, int N, int E)
{
  int t = blockIdx.x * 256 + threadIdx.x;
  if (t >= N * 8) return;
  int n = t >> 3;
  int h = t & 7;
  float qh = q[t];
  int j0 = row_ptr[n], j1 = row_ptr[n + 1];
  float num = 0.f, den = 0.f;
  for (int j = j0; j < j1; ++j) {
    float key = kvE[(size_t)j * 16 + 8 + h];
    float val = kvE[(size_t)j * 16 + h];
    float lg = fminf(key * qh, 60.0f);
    float w = scaleP[j] * __expf(lg);
    num += w * val;
    den += w;
  }
  agg[t] = num / fmaxf(den, 1e-20f);
}

// ---------------- feats gather (kvE layout) ----------------
__global__ __launch_bounds__(256) void k_gather_feats(
    const int* __restrict__ row_ptr, const float* __restrict__ kvE,
    float* __restrict__ feats, int N, int E)
{
  int t = blockIdx.x * 256 + threadIdx.x;
  if (t >= N * 16) return;
  int n = t >> 4;
  int o = t & 15;
  int j0 = row_ptr[n], j1 = row_ptr[n + 1];
  float a = 0.f;
  for (int j = j0; j < j1; ++j) a += kvE[(size_t)j * 16 + o];
  feats[t] = a;
}

// ---------------- node update ----------------
__global__ __launch_bounds__(256) void k_node_update(
    const float* __restrict__ agg, const float* __restrict__ xin,
    const float* __restrict__ Wproj, const float* __restrict__ Wq_next,
    float* __restrict__ xout, float* __restrict__ q, int N)
{
  int n = blockIdx.x * 256 + threadIdx.x;
  if (n >= N) return;
  float cat[24];
  load8(agg + (size_t)n * 8, cat);
  load16(xin + (size_t)n * 16, cat + 8);
  float xn[16];
#pragma unroll
  for (int o = 0; o < 16; o++) {
    float a = 0.f;
#pragma unroll
    for (int j = 0; j < 24; j++) a += Wproj[o * 24 + j] * cat[j];
    xn[o] = a;
  }
  store16(xout + (size_t)n * 16, xn);
  float qv[8];
#pragma unroll
  for (int h = 0; h < 8; h++) {
    float a = 0.f;
#pragma unroll
    for (int i = 0; i < 16; i++) a += Wq_next[h * 16 + i] * xn[i];
    qv[h] = a;
  }
  store8(q + (size_t)n * 8, qv);
}

// ---------------- final node MLP -> per-block partials ----------------
__global__ __launch_bounds__(256) void k_node_final(
    const float* __restrict__ x, const float* __restrict__ semb,
    const float* __restrict__ feats, const float* __restrict__ Wself,
    const float* __restrict__ mW1, const float* __restrict__ mb1,
    const float* __restrict__ mW2, const float* __restrict__ mb2,
    const float* __restrict__ mW3, const float* __restrict__ mb3,
    float* __restrict__ learn_part, int N)
{
  int n = blockIdx.x * 256 + threadIdx.x;
  float learned = 0.f;
  if (n < N) {
    float xv[16], ft[16], sb[16];
    load16(x + (size_t)n * 16, xv);
    load16(feats + (size_t)n * 16, ft);
    load16(semb + (size_t)n * 16, sb);
    float cat[32];
#pragma unroll
    for (int i = 0; i < 16; i++) cat[i] = sb[i];
#pragma unroll
    for (int o = 0; o < 16; o++) {
      float a = ft[o];
#pragma unroll
      for (int i = 0; i < 16; i++) a += Wself[o * 16 + i] * xv[i];
      cat[16 + o] = a;
    }
    float hh[16];
#pragma unroll
    for (int j = 0; j < 16; j++) {
      float a = mb1[j];
#pragma unroll
      for (int k = 0; k < 32; k++) a += cat[k] * mW1[k * 16 + j];
      hh[j] = siluf(a);
    }
    float h2[16];
#pragma unroll
    for (int j = 0; j < 16; j++) {
      float a = mb2[j];
#pragma unroll
      for (int k = 0; k < 16; k++) a += hh[k] * mW2[k * 16 + j];
      h2[j] = siluf(a);
    }
    float a = mb3[0];
#pragma unroll
    for (int k = 0; k < 16; k++) a += h2[k] * mW3[k];
    learned = a;
  }
  block_reduce_store(learned, learn_part);
}

// ---------------- final reduction ----------------
__global__ __launch_bounds__(256) void k_finalize(
    const float* __restrict__ coul_part, int nc,
    const float* __restrict__ learn_part, int nl,
    float* __restrict__ out)
{
  __shared__ float sred[4];
  int tid = threadIdx.x;
  float v = 0.f;
  for (int i = tid; i < nc; i += 256) v += coul_part[i];
  for (int i = tid; i < nl; i += 256) v += learn_part[i];
#pragma unroll
  for (int off = 32; off > 0; off >>= 1) v += __shfl_down(v, off, 64);
  if ((tid & 63) == 0) sred[tid >> 6] = v;
  __syncthreads();
  if (tid == 0) out[0] = sred[0] + sred[1] + sred[2] + sred[3];
}

extern "C" void kernel_launch(void* const* d_in, const int* in_sizes, int n_in,
                              void* d_out, int out_size, void* d_ws, size_t ws_size,
                              hipStream_t stream)
{
  const int*   species = (const int*)d_in[0];
  const int*   src     = (const int*)d_in[1];
  const int*   dst     = (const int*)d_in[2];
  const float* rel_pos = (const float*)d_in[3];
  const float* emb     = (const float*)d_in[4];
  const float* kv_W1   = (const float*)d_in[5];
  const float* kv_b1   = (const float*)d_in[6];
  const float* kv_W2   = (const float*)d_in[7];
  const float* kv_b2   = (const float*)d_in[8];
  const float* kv_W3   = (const float*)d_in[9];
  const float* kv_b3   = (const float*)d_in[10];
  const float* Wq      = (const float*)d_in[11];
  const float* Wproj   = (const float*)d_in[12];
  const float* fin_W1  = (const float*)d_in[13];
  const float* fin_b1  = (const float*)d_in[14];
  const float* fin_W2  = (const float*)d_in[15];
  const float* fin_b2  = (const float*)d_in[16];
  const float* fin_W3  = (const float*)d_in[17];
  const float* fin_b3  = (const float*)d_in[18];
  const float* Wself   = (const float*)d_in[19];
  const float* mlp_W1  = (const float*)d_in[20];
  const float* mlp_b1  = (const float*)d_in[21];
  const float* mlp_W2  = (const float*)d_in[22];
  const float* mlp_b2  = (const float*)d_in[23];
  const float* mlp_W3  = (const float*)d_in[24];
  const float* mlp_b3  = (const float*)d_in[25];

  const int N = in_sizes[0];
  const int E = in_sizes[1];
  const int nblk_e = (E + 255) / 256;
  const int nblk_n = (N + 255) / 256;

  char* p = (char*)d_ws;
  auto alloc = [&](size_t bytes) -> void* {
    void* r = (void*)p;
    p += (bytes + 255) & ~(size_t)255;
    return r;
  };
  float* dist_   = (float*)alloc((size_t)E * 4);
  float* scale_  = (float*)alloc((size_t)E * 4);
  float* distP   = (float*)alloc((size_t)E * 4);
  float* scaleP  = (float*)alloc((size_t)E * 4);
  int*   srcP    = (int*)  alloc((size_t)E * 4);
  float* ef      = (float*)alloc((size_t)E * 16 * 4);
  float* kvE     = (float*)alloc((size_t)E * 16 * 4);
  float* xA      = (float*)alloc((size_t)N * 16 * 4);
  float* xB      = (float*)alloc((size_t)N * 16 * 4);
  float* q       = (float*)alloc((size_t)N * 8 * 4);
  float* semb    = (float*)alloc((size_t)N * 16 * 4);
  float* agg     = (float*)alloc((size_t)N * 8 * 4);
  float* feats   = (float*)alloc((size_t)N * 16 * 4);
  int*   cnt     = (int*)  alloc((size_t)N * 4);
  int*   row_ptr = (int*)  alloc((size_t)(N + 1) * 4);
  int*   row_cur = (int*)  alloc((size_t)N * 4);
  int*   bsum    = (int*)  alloc(128 * 4);
  int*   boff    = (int*)  alloc(128 * 4);
  uint4* WF      = (uint4*)alloc((size_t)5 * 19 * 64 * 16);
  float* coul_part  = (float*)alloc((size_t)nblk_e * 4);
  float* learn_part = (float*)alloc((size_t)nblk_n * 4);

  dim3 blk(256);
  dim3 egrid(nblk_e);
  dim3 cgrid(E / 64);
  dim3 ngrid(nblk_n);
  dim3 n8grid((N * 8 + 255) / 256);
  dim3 n16grid((N * 16 + 255) / 256);

  hipMemsetAsync(cnt, 0, (size_t)N * 4, stream);

  k_prepack<<<dim3(24), blk, 0, stream>>>(kv_W3, kv_b3, fin_W3, fin_b3,
                                          kv_W2, fin_W2, WF);

  k_pre<<<egrid, blk, 0, stream>>>(species, src, dst, rel_pos, dist_, scale_,
                                   coul_part, E);
  k_hist<<<egrid, blk, 0, stream>>>(dst, cnt, E);
  k_scan1<<<ngrid, blk, 0, stream>>>(cnt, row_ptr, bsum);
  k_scan2<<<dim3(1), dim3(128), 0, stream>>>(bsum, boff);
  k_scan3<<<ngrid, blk, 0, stream>>>(row_ptr, row_cur, boff, N, E);
  k_scatter<<<egrid, blk, 0, stream>>>(src, dst, dist_, scale_, row_cur,
                                       srcP, distP, scaleP, E);

  k_node_init<<<ngrid, blk, 0, stream>>>(species, emb, Wq, xA, semb, q, N);

  float* xin = xA;
  float* xout = xB;
  for (int l = 0; l < 4; l++) {
    const float* W1 = kv_W1 + (size_t)l * 16 * 32;
    const float* B1 = kv_b1 + (size_t)l * 32;
    const float* B2 = kv_b2 + (size_t)l * 32;
    const uint4* WFl = WF + (size_t)l * 19 * 64;
    const float* Wqn = Wq + (size_t)((l < 3) ? (l + 1) : 0) * 8 * 16;
    if (l == 0) {
      k_edge_conv<0><<<cgrid, blk, 0, stream>>>(srcP, scaleP, distP, ef, xin,
                                                W1, B1, B2, WFl, kvE, E);
    } else if (l == 1) {
      k_edge_conv<1><<<cgrid, blk, 0, stream>>>(srcP, scaleP, distP, ef, xin,
                                                W1, B1, B2, WFl, kvE, E);
    } else {
      k_edge_conv<2><<<cgrid, blk, 0, stream>>>(srcP, scaleP, distP, ef, xin,
                                                W1, B1, B2, WFl, kvE, E);
    }
    k_gather_agg<<<n8grid, blk, 0, stream>>>(row_ptr, scaleP, kvE, q, agg, N, E);
    k_node_update<<<ngrid, blk, 0, stream>>>(agg, xin, Wproj + (size_t)l * 16 * 24, Wqn,
                                             xout, q, N);
    float* tmp = xin; xin = xout; xout = tmp;
  }

  k_edge_conv<3><<<cgrid, blk, 0, stream>>>(srcP, scaleP, distP, ef, xin,
                                            fin_W1, fin_b1, fin_b2,
                                            WF + (size_t)4 * 19 * 64, kvE, E);
  k_gather_feats<<<n16grid, blk, 0, stream>>>(row_ptr, kvE, feats, N, E);
  k_node_final<<<ngrid, blk, 0, stream>>>(xin, semb, feats, Wself,
                                          mlp_W1, mlp_b1, mlp_W2, mlp_b2, mlp_W3, mlp_b3,
                                          learn_part, N);
  k_finalize<<<dim3(1), blk, 0, stream>>>(coul_part, nblk_e, learn_part, nblk_n,
                                          (float*)d_out);
}